// Round 1
// baseline (321.143 us; speedup 1.0000x reference)
//
#include <hip/hip_runtime.h>

#define L_ 128
#define T_ 128
#define P_ 255
#define MJ 64      // even m: m = 2j, j in [0,64)
#define B_ 16
#define CI 8
#define CO 8

// ---------------- K0: trig tables C[j][p]=cos(2pi*2j*p/255), S likewise ----
__global__ void k_tables(float* __restrict__ C, float* __restrict__ S) {
  int idx = blockIdx.x * 256 + threadIdx.x;
  if (idx >= MJ * P_) return;
  int j = idx / P_, p = idx - j * P_;
  double ang = (6.283185307179586476925286766559 / (double)P_) * (double)(2 * j) * (double)p;
  C[idx] = (float)cos(ang);
  S[idx] = (float)sin(ang);
}

// ---------------- K1: forward DFT (even m only), in [R][T][P] -> [MJ][R][T] -
template<int R>
__global__ __launch_bounds__(256) void k_dft_fwd(
    const float* __restrict__ in, const float* __restrict__ Ct,
    const float* __restrict__ St, float* __restrict__ outr, float* __restrict__ outi) {
  const int r = blockIdx.x;
  const int t0 = blockIdx.y * 64;
  const int tid = threadIdx.x;
  const int tt = tid & 15;   // t lane
  const int mm = tid >> 4;   // j group
  __shared__ float xs[64 * 51], cs[64 * 51], ss[64 * 51];
  float accr[4][4] = {{0.f}};
  float acci[4][4] = {{0.f}};
  const float* xrow = in + (r * T_ + t0) * P_;
  for (int p0 = 0; p0 < P_; p0 += 51) {
    __syncthreads();
    for (int idx = tid; idx < 64 * 51; idx += 256) {
      int row = idx / 51, pp = idx - row * 51;
      xs[idx] = xrow[row * P_ + p0 + pp];
      cs[idx] = Ct[row * P_ + p0 + pp];
      ss[idx] = St[row * P_ + p0 + pp];
    }
    __syncthreads();
    for (int pp = 0; pp < 51; ++pp) {
      float xv[4], cv[4], sv[4];
      #pragma unroll
      for (int k = 0; k < 4; ++k) xv[k] = xs[(k * 16 + tt) * 51 + pp];
      #pragma unroll
      for (int q = 0; q < 4; ++q) {
        cv[q] = cs[(q * 16 + mm) * 51 + pp];
        sv[q] = ss[(q * 16 + mm) * 51 + pp];
      }
      #pragma unroll
      for (int k = 0; k < 4; ++k)
        #pragma unroll
        for (int q = 0; q < 4; ++q) {
          accr[k][q] = fmaf(xv[k],  cv[q], accr[k][q]);
          acci[k][q] = fmaf(xv[k], -sv[q], acci[k][q]);
        }
    }
  }
  const float inv = 1.0f / (float)P_;
  #pragma unroll
  for (int q = 0; q < 4; ++q) {
    int j = q * 16 + mm;
    #pragma unroll
    for (int k = 0; k < 4; ++k) {
      int t = t0 + k * 16 + tt;
      outr[(j * R + r) * T_ + t] = accr[k][q] * inv;
      outi[(j * R + r) * T_ + t] = acci[k][q] * inv;
    }
  }
}

// ---------------- K2: Legendre analysis: XL[j][r][l] = sum_t Pinv[m][l][t] X[j][r][t]
template<int R>
__global__ __launch_bounds__(256) void k_leg_fwd(
    const float* __restrict__ Xr, const float* __restrict__ Xi,
    const float* __restrict__ Pinv, float* __restrict__ XLr, float* __restrict__ XLi) {
  const int j = blockIdx.x;
  constexpr int NRT = R / 64;
  const int r0 = (blockIdx.y % NRT) * 64;
  const int l0 = (blockIdx.y / NRT) * 64;
  const int tid = threadIdx.x;
  const int ll = tid & 15;
  const int rr = tid >> 4;
  __shared__ float Ar[64 * 17], Ai[64 * 17], Pl[64 * 17];
  float accr[4][4] = {{0.f}}, acci[4][4] = {{0.f}};
  const int mfull = 127 + 2 * j;
  for (int tk = 0; tk < T_; tk += 16) {
    __syncthreads();
    for (int idx = tid; idx < 64 * 16; idx += 256) {
      int row = idx >> 4, tc = idx & 15;
      Ar[row * 17 + tc] = Xr[(j * R + r0 + row) * T_ + tk + tc];
      Ai[row * 17 + tc] = Xi[(j * R + r0 + row) * T_ + tk + tc];
      Pl[row * 17 + tc] = Pinv[(mfull * L_ + l0 + row) * T_ + tk + tc];
    }
    __syncthreads();
    for (int tc = 0; tc < 16; ++tc) {
      float ar[4], av[4], pv[4];
      #pragma unroll
      for (int kr = 0; kr < 4; ++kr) {
        ar[kr] = Ar[(kr * 16 + rr) * 17 + tc];
        av[kr] = Ai[(kr * 16 + rr) * 17 + tc];
      }
      #pragma unroll
      for (int kl = 0; kl < 4; ++kl) pv[kl] = Pl[(kl * 16 + ll) * 17 + tc];
      #pragma unroll
      for (int kr = 0; kr < 4; ++kr)
        #pragma unroll
        for (int kl = 0; kl < 4; ++kl) {
          accr[kr][kl] = fmaf(ar[kr], pv[kl], accr[kr][kl]);
          acci[kr][kl] = fmaf(av[kr], pv[kl], acci[kr][kl]);
        }
    }
  }
  #pragma unroll
  for (int kr = 0; kr < 4; ++kr) {
    int rrow = r0 + kr * 16 + rr;
    #pragma unroll
    for (int kl = 0; kl < 4; ++kl) {
      int l = l0 + kl * 16 + ll;
      XLr[(j * R + rrow) * L_ + l] = accr[kr][kl];
      XLi[(j * R + rrow) * L_ + l] = acci[kr][kl];
    }
  }
}

// ---------------- K3: harmonic product, sum over input channels -------------
__global__ __launch_bounds__(128) void k_hprod(
    const float* __restrict__ XLr, const float* __restrict__ XLi,
    const float* __restrict__ WLr, const float* __restrict__ WLi,
    float* __restrict__ OLr, float* __restrict__ OLi) {
  const int blk = blockIdx.x;        // j*128 + b*8 + o
  const int l = threadIdx.x;         // 0..127
  const int o = blk & 7;
  const int b = (blk >> 3) & 15;
  const int j = blk >> 7;
  float accr = 0.f, acci = 0.f;
  #pragma unroll
  for (int i = 0; i < CI; ++i) {
    float xr = XLr[(j * 128 + b * CI + i) * L_ + l];
    float xi = XLi[(j * 128 + b * CI + i) * L_ + l];
    float wr = WLr[(j * 64 + o * CI + i) * L_ + l];
    float wi = WLi[(j * 64 + o * CI + i) * L_ + l];
    accr += xr * wr - xi * wi;
    acci += xr * wi + xi * wr;
  }
  OLr[(j * 128 + b * CO + o) * L_ + l] = accr;
  OLi[(j * 128 + b * CO + o) * L_ + l] = acci;
}

// ---------------- K4: Legendre synthesis: G[j][r][t] = sum_l Psyn[m][t][l] OL[j][r][l]
__global__ __launch_bounds__(256) void k_leg_inv(
    const float* __restrict__ OLr, const float* __restrict__ OLi,
    const float* __restrict__ Psyn, float* __restrict__ Gr, float* __restrict__ Gi) {
  const int j = blockIdx.x;
  const int r0 = (blockIdx.y & 1) * 64;
  const int t0 = (blockIdx.y >> 1) * 64;
  const int tid = threadIdx.x;
  const int tl = tid & 15;
  const int rr = tid >> 4;
  __shared__ float Or_[64 * 17], Oi_[64 * 17], Ps[64 * 17];
  float accr[4][4] = {{0.f}}, acci[4][4] = {{0.f}};
  const int mfull = 127 + 2 * j;
  for (int lk = 0; lk < L_; lk += 16) {
    __syncthreads();
    for (int idx = tid; idx < 64 * 16; idx += 256) {
      int row = idx >> 4, lc = idx & 15;
      Or_[row * 17 + lc] = OLr[(j * 128 + r0 + row) * L_ + lk + lc];
      Oi_[row * 17 + lc] = OLi[(j * 128 + r0 + row) * L_ + lk + lc];
      Ps[row * 17 + lc]  = Psyn[(mfull * T_ + t0 + row) * L_ + lk + lc];
    }
    __syncthreads();
    for (int lc = 0; lc < 16; ++lc) {
      float orv[4], oiv[4], pv[4];
      #pragma unroll
      for (int kr = 0; kr < 4; ++kr) {
        orv[kr] = Or_[(kr * 16 + rr) * 17 + lc];
        oiv[kr] = Oi_[(kr * 16 + rr) * 17 + lc];
      }
      #pragma unroll
      for (int kt = 0; kt < 4; ++kt) pv[kt] = Ps[(kt * 16 + tl) * 17 + lc];
      #pragma unroll
      for (int kr = 0; kr < 4; ++kr)
        #pragma unroll
        for (int kt = 0; kt < 4; ++kt) {
          accr[kr][kt] = fmaf(orv[kr], pv[kt], accr[kr][kt]);
          acci[kr][kt] = fmaf(oiv[kr], pv[kt], acci[kr][kt]);
        }
    }
  }
  const float scale = (j == 0) ? 1.0f : 2.0f;   // weight for m>0 (conjugate pair)
  #pragma unroll
  for (int kr = 0; kr < 4; ++kr) {
    int r = r0 + kr * 16 + rr;
    #pragma unroll
    for (int kt = 0; kt < 4; ++kt) {
      int t = t0 + kt * 16 + tl;
      Gr[(j * 128 + r) * T_ + t] = accr[kr][kt] * scale;
      Gi[(j * 128 + r) * T_ + t] = acci[kr][kt] * scale;
    }
  }
}

// ---------------- K5: inverse DFT (real part) + bias ------------------------
__global__ __launch_bounds__(256) void k_idft(
    const float* __restrict__ Gr, const float* __restrict__ Gi,
    const float* __restrict__ Ct, const float* __restrict__ St,
    const float* __restrict__ bias, float* __restrict__ out) {
  const int r = blockIdx.x;        // b*8+o
  const int t0 = blockIdx.y * 64;
  const int o = r & 7;
  const int tid = threadIdx.x;
  const int pl = tid & 15;
  const int tg = tid >> 4;
  __shared__ float Gre[64 * 64], Gim[64 * 64];  // [j][t-tile]
  __shared__ float cs[63 * 64], ss[63 * 64];    // rows j=1..63 (j=0: C=1,S=0)
  for (int idx = tid; idx < 64 * 64; idx += 256) {
    int jj = idx >> 6, tc = idx & 63;
    Gre[idx] = Gr[(jj * 128 + r) * T_ + t0 + tc];
    Gim[idx] = Gi[(jj * 128 + r) * T_ + t0 + tc];
  }
  const float bv = bias[o];
  for (int p0 = 0; p0 < P_; p0 += 64) {
    __syncthreads();
    for (int idx = tid; idx < 63 * 64; idx += 256) {
      int jj = idx >> 6, pc = idx & 63;
      int p = p0 + pc;
      cs[idx] = (p < P_) ? Ct[(jj + 1) * P_ + p] : 0.f;
      ss[idx] = (p < P_) ? St[(jj + 1) * P_ + p] : 0.f;
    }
    __syncthreads();
    float acc[4][4];
    #pragma unroll
    for (int kt = 0; kt < 4; ++kt) {
      float g0 = Gre[kt * 16 + tg];          // j=0 term: C=1, S=0
      #pragma unroll
      for (int kp = 0; kp < 4; ++kp) acc[kt][kp] = bv + g0;
    }
    for (int jj = 1; jj < 64; ++jj) {
      float gr[4], gi[4], cv[4], sv[4];
      #pragma unroll
      for (int kt = 0; kt < 4; ++kt) {
        gr[kt] = Gre[jj * 64 + kt * 16 + tg];
        gi[kt] = Gim[jj * 64 + kt * 16 + tg];
      }
      #pragma unroll
      for (int kp = 0; kp < 4; ++kp) {
        cv[kp] = cs[(jj - 1) * 64 + kp * 16 + pl];
        sv[kp] = ss[(jj - 1) * 64 + kp * 16 + pl];
      }
      #pragma unroll
      for (int kt = 0; kt < 4; ++kt)
        #pragma unroll
        for (int kp = 0; kp < 4; ++kp) {
          acc[kt][kp] = fmaf(gr[kt],  cv[kp], acc[kt][kp]);
          acc[kt][kp] = fmaf(gi[kt], -sv[kp], acc[kt][kp]);
        }
    }
    #pragma unroll
    for (int kt = 0; kt < 4; ++kt) {
      int t = t0 + kt * 16 + tg;
      #pragma unroll
      for (int kp = 0; kp < 4; ++kp) {
        int p = p0 + kp * 16 + pl;
        if (p < P_) out[(r * T_ + t) * P_ + p] = acc[kt][kp];
      }
    }
  }
}

extern "C" void kernel_launch(void* const* d_in, const int* in_sizes, int n_in,
                              void* d_out, int out_size, void* d_ws, size_t ws_size,
                              hipStream_t stream) {
  const float* x    = (const float*)d_in[0];
  const float* w    = (const float*)d_in[1];
  const float* bias = (const float*)d_in[2];
  const float* Psyn = (const float*)d_in[3];
  const float* Pinv = (const float*)d_in[4];
  float* out = (float*)d_out;

  float* ws = (float*)d_ws;
  float* Ctab = ws;                          // MJ*P_
  float* Stab = Ctab + MJ * P_;
  float* bufA = Stab + MJ * P_;              // 2 * MJ*128*T_ : X then OL
  float* Xr = bufA;
  float* Xi = bufA + MJ * 128 * T_;
  float* OLr = Xr;                           // reuse after X consumed
  float* OLi = Xi;
  float* bufB = bufA + 2 * MJ * 128 * T_;    // 2 * MJ*128*L_ : XL then G
  float* XLr = bufB;
  float* XLi = bufB + MJ * 128 * L_;
  float* Gr2 = XLr;                          // reuse after XL consumed
  float* Gi2 = XLi;
  float* bufW = bufB + 2 * MJ * 128 * L_;    // 2 * MJ*64*T_
  float* Wr = bufW;
  float* Wi = bufW + MJ * 64 * T_;
  float* bufWL = bufW + 2 * MJ * 64 * T_;    // 2 * MJ*64*L_
  float* WLr = bufWL;
  float* WLi = bufWL + MJ * 64 * L_;

  k_tables<<<(MJ * P_ + 255) / 256, 256, 0, stream>>>(Ctab, Stab);
  k_dft_fwd<128><<<dim3(128, 2), 256, 0, stream>>>(x, Ctab, Stab, Xr, Xi);
  k_dft_fwd<64><<<dim3(64, 2), 256, 0, stream>>>(w, Ctab, Stab, Wr, Wi);
  k_leg_fwd<128><<<dim3(64, 4), 256, 0, stream>>>(Xr, Xi, Pinv, XLr, XLi);
  k_leg_fwd<64><<<dim3(64, 2), 256, 0, stream>>>(Wr, Wi, Pinv, WLr, WLi);
  k_hprod<<<MJ * B_ * CO, 128, 0, stream>>>(XLr, XLi, WLr, WLi, OLr, OLi);
  k_leg_inv<<<dim3(64, 4), 256, 0, stream>>>(OLr, OLi, Psyn, Gr2, Gi2);
  k_idft<<<dim3(128, 2), 256, 0, stream>>>(Gr2, Gi2, Ctab, Stab, bias, out);
}

// Round 2
// 230.043 us; speedup vs baseline: 1.3960x; 1.3960x over previous
//
#include <hip/hip_runtime.h>

#define L_ 128
#define T_ 128
#define P_ 255
#define MJ 64      // even m: m = 2j
#define RX 128     // x rows (b*ci)
#define RW 64      // w rows (o*ci)
#define RT 192     // fused rows

// ---------------- K0: trig tables C[j][p]=cos(2pi*2j*p/255) -----------------
__global__ void k_tables(float* __restrict__ C, float* __restrict__ S) {
  int idx = blockIdx.x * 256 + threadIdx.x;
  if (idx >= MJ * P_) return;
  int j = idx / P_, p = idx - j * P_;
  double ang = (6.283185307179586476925286766559 / (double)P_) * (double)(2 * j) * (double)p;
  C[idx] = (float)cos(ang);
  S[idx] = (float)sin(ang);
}

// ---------------- K1: fused fwd DFT for x and w: [r'][t][p] -> X[j][r'][t] --
__global__ __launch_bounds__(256) void k_dft(
    const float* __restrict__ x, const float* __restrict__ w,
    const float* __restrict__ Ct, const float* __restrict__ St,
    float* __restrict__ Xr, float* __restrict__ Xi) {
  const int r  = blockIdx.x;             // 0..191
  const int t0 = (blockIdx.y & 1) * 64;
  const int j0 = (blockIdx.y >> 1) * 32;
  const int tid = threadIdx.x;
  const int tl = tid & 15;               // t lane
  const int jg = tid >> 4;               // j group (16)
  __shared__ float xs[64 * 51], cs[32 * 51], ss[32 * 51];
  float accr[4][2] = {{0.f}}, acci[4][2] = {{0.f}};
  const float* row = (r < RX) ? (x + (size_t)r * T_ * P_)
                              : (w + (size_t)(r - RX) * T_ * P_);
  for (int p0 = 0; p0 < P_; p0 += 51) {
    __syncthreads();
    for (int idx = tid; idx < 64 * 51; idx += 256) {
      int tt = idx / 51, pp = idx - tt * 51;
      xs[idx] = row[(t0 + tt) * P_ + p0 + pp];
    }
    for (int idx = tid; idx < 32 * 51; idx += 256) {
      int jj = idx / 51, pp = idx - jj * 51;
      cs[idx] = Ct[(j0 + jj) * P_ + p0 + pp];
      ss[idx] = St[(j0 + jj) * P_ + p0 + pp];
    }
    __syncthreads();
    for (int pp = 0; pp < 51; ++pp) {
      float xv[4], cv[2], sv[2];
      #pragma unroll
      for (int k = 0; k < 4; ++k) xv[k] = xs[(k * 16 + tl) * 51 + pp];
      #pragma unroll
      for (int q = 0; q < 2; ++q) {
        cv[q] = cs[(q * 16 + jg) * 51 + pp];
        sv[q] = ss[(q * 16 + jg) * 51 + pp];
      }
      #pragma unroll
      for (int k = 0; k < 4; ++k)
        #pragma unroll
        for (int q = 0; q < 2; ++q) {
          accr[k][q] = fmaf(xv[k],  cv[q], accr[k][q]);
          acci[k][q] = fmaf(xv[k], -sv[q], acci[k][q]);
        }
    }
  }
  const float inv = 1.0f / (float)P_;
  #pragma unroll
  for (int q = 0; q < 2; ++q) {
    int j = j0 + q * 16 + jg;
    #pragma unroll
    for (int k = 0; k < 4; ++k) {
      int t = t0 + k * 16 + tl;
      Xr[((size_t)j * RT + r) * T_ + t] = accr[k][q] * inv;
      Xi[((size_t)j * RT + r) * T_ + t] = acci[k][q] * inv;
    }
  }
}

// ---------------- K2: Legendre analysis (fused x+w): XL[j][l][r'] -----------
__global__ __launch_bounds__(256) void k_leg_fwd(
    const float* __restrict__ Xr, const float* __restrict__ Xi,
    const float* __restrict__ Pinv, float* __restrict__ XLr, float* __restrict__ XLi) {
  const int j  = blockIdx.x;
  const int rt = blockIdx.y % 6;        // 6 r-tiles of 32
  const int lt = blockIdx.y / 6;        // 2 l-tiles of 64
  const int r0 = rt * 32, l0 = lt * 64;
  const int tid = threadIdx.x;
  const int rl = tid & 15;              // r lane
  const int lg = tid >> 4;              // l group
  __shared__ float Ar[32 * 17], Ai[32 * 17], Pl[64 * 17];
  float accr[2][4] = {{0.f}}, acci[2][4] = {{0.f}};
  const int m = 127 + 2 * j;
  for (int tk = 0; tk < T_; tk += 16) {
    __syncthreads();
    for (int idx = tid; idx < 32 * 16; idx += 256) {
      int row = idx >> 4, tc = idx & 15;
      Ar[row * 17 + tc] = Xr[((size_t)j * RT + r0 + row) * T_ + tk + tc];
      Ai[row * 17 + tc] = Xi[((size_t)j * RT + r0 + row) * T_ + tk + tc];
    }
    for (int idx = tid; idx < 64 * 16; idx += 256) {
      int row = idx >> 4, tc = idx & 15;
      Pl[row * 17 + tc] = Pinv[((size_t)m * L_ + l0 + row) * T_ + tk + tc];
    }
    __syncthreads();
    for (int tc = 0; tc < 16; ++tc) {
      float ar[2], av[2], pv[4];
      #pragma unroll
      for (int kr = 0; kr < 2; ++kr) {
        ar[kr] = Ar[(kr * 16 + rl) * 17 + tc];
        av[kr] = Ai[(kr * 16 + rl) * 17 + tc];
      }
      #pragma unroll
      for (int kl = 0; kl < 4; ++kl) pv[kl] = Pl[(kl * 16 + lg) * 17 + tc];
      #pragma unroll
      for (int kr = 0; kr < 2; ++kr)
        #pragma unroll
        for (int kl = 0; kl < 4; ++kl) {
          accr[kr][kl] = fmaf(ar[kr], pv[kl], accr[kr][kl]);
          acci[kr][kl] = fmaf(av[kr], pv[kl], acci[kr][kl]);
        }
    }
  }
  #pragma unroll
  for (int kl = 0; kl < 4; ++kl) {
    int l = l0 + kl * 16 + lg;
    #pragma unroll
    for (int kr = 0; kr < 2; ++kr) {
      int r = r0 + kr * 16 + rl;
      XLr[((size_t)j * L_ + l) * RT + r] = accr[kr][kl];
      XLi[((size_t)j * L_ + l) * RT + r] = acci[kr][kl];
    }
  }
}

// ---------------- K3: harmonic product: OL[j][l][b*8+o] ---------------------
__global__ __launch_bounds__(256) void k_hprod(
    const float* __restrict__ XLr, const float* __restrict__ XLi,
    float* __restrict__ OLr, float* __restrict__ OLi) {
  const int j  = blockIdx.x;
  const int l0 = blockIdx.y * 8;
  const int tid = threadIdx.x;
  __shared__ float Xs[2][8][128], Ws[2][8][64];
  for (int idx = tid; idx < 8 * 128; idx += 256) {
    int ll = idx >> 7, rr = idx & 127;
    size_t base = ((size_t)j * L_ + l0 + ll) * RT;
    Xs[0][ll][rr] = XLr[base + rr];
    Xs[1][ll][rr] = XLi[base + rr];
  }
  for (int idx = tid; idx < 8 * 64; idx += 256) {
    int ll = idx >> 6, rr = idx & 63;
    size_t base = ((size_t)j * L_ + l0 + ll) * RT + RX;
    Ws[0][ll][rr] = XLr[base + rr];
    Ws[1][ll][rr] = XLi[base + rr];
  }
  __syncthreads();
  const int ll  = tid >> 5;   // 8 l rows
  const int bo0 = tid & 31;
  #pragma unroll
  for (int k = 0; k < 4; ++k) {
    int bo = bo0 + k * 32;
    int b = bo >> 3, o = bo & 7;
    float accr = 0.f, acci = 0.f;
    #pragma unroll
    for (int i = 0; i < 8; ++i) {
      float xr = Xs[0][ll][b * 8 + i], xi = Xs[1][ll][b * 8 + i];
      float wr = Ws[0][ll][o * 8 + i], wi = Ws[1][ll][o * 8 + i];
      accr += xr * wr - xi * wi;
      acci += xr * wi + xi * wr;
    }
    OLr[((size_t)j * L_ + l0 + ll) * 128 + bo] = accr;
    OLi[((size_t)j * L_ + l0 + ll) * 128 + bo] = acci;
  }
}

// ---------------- K4: Legendre synthesis: G[j][r][t] ------------------------
__global__ __launch_bounds__(256) void k_leg_inv(
    const float* __restrict__ OLr, const float* __restrict__ OLi,
    const float* __restrict__ Psyn, float* __restrict__ Gr, float* __restrict__ Gi) {
  const int j  = blockIdx.x;
  const int rt = blockIdx.y & 3;        // 4 r-tiles of 32
  const int tt = blockIdx.y >> 2;       // 2 t-tiles of 64
  const int r0 = rt * 32, t0 = tt * 64;
  const int tid = threadIdx.x;
  const int tl = tid & 15;              // t lane
  const int rg = tid >> 4;              // r group
  __shared__ float Osr[32 * 17], Osi[32 * 17], Ps[64 * 17];
  float accr[2][4] = {{0.f}}, acci[2][4] = {{0.f}};
  const int m = 127 + 2 * j;
  for (int lk = 0; lk < L_; lk += 16) {
    __syncthreads();
    for (int idx = tid; idx < 32 * 16; idx += 256) {
      int row = idx & 31, lc = idx >> 5;            // coalesced over r
      size_t base = ((size_t)j * L_ + lk + lc) * 128 + r0;
      Osr[row * 17 + lc] = OLr[base + row];
      Osi[row * 17 + lc] = OLi[base + row];
    }
    for (int idx = tid; idx < 64 * 16; idx += 256) {
      int row = idx >> 4, lc = idx & 15;
      Ps[row * 17 + lc] = Psyn[((size_t)m * T_ + t0 + row) * L_ + lk + lc];
    }
    __syncthreads();
    for (int lc = 0; lc < 16; ++lc) {
      float orv[2], oiv[2], pv[4];
      #pragma unroll
      for (int kr = 0; kr < 2; ++kr) {
        orv[kr] = Osr[(kr * 16 + rg) * 17 + lc];
        oiv[kr] = Osi[(kr * 16 + rg) * 17 + lc];
      }
      #pragma unroll
      for (int kt = 0; kt < 4; ++kt) pv[kt] = Ps[(kt * 16 + tl) * 17 + lc];
      #pragma unroll
      for (int kr = 0; kr < 2; ++kr)
        #pragma unroll
        for (int kt = 0; kt < 4; ++kt) {
          accr[kr][kt] = fmaf(orv[kr], pv[kt], accr[kr][kt]);
          acci[kr][kt] = fmaf(oiv[kr], pv[kt], acci[kr][kt]);
        }
    }
  }
  const float scale = (j == 0) ? 1.0f : 2.0f;
  #pragma unroll
  for (int kr = 0; kr < 2; ++kr) {
    int r = r0 + kr * 16 + rg;
    #pragma unroll
    for (int kt = 0; kt < 4; ++kt) {
      int t = t0 + kt * 16 + tl;
      Gr[((size_t)j * 128 + r) * T_ + t] = accr[kr][kt] * scale;
      Gi[((size_t)j * 128 + r) * T_ + t] = acci[kr][kt] * scale;
    }
  }
}

// ---------------- K5: inverse DFT (real part) + bias, k-chunked over j ------
__global__ __launch_bounds__(256) void k_idft(
    const float* __restrict__ Gr, const float* __restrict__ Gi,
    const float* __restrict__ Ct, const float* __restrict__ St,
    const float* __restrict__ bias, float* __restrict__ out) {
  const int r  = blockIdx.x;            // 0..127 = b*8+o
  const int pt = blockIdx.y & 3;        // 4 p-tiles of 64
  const int tt = blockIdx.y >> 2;       // 2 t-tiles of 64
  const int p0 = pt * 64, t0 = tt * 64;
  const int tid = threadIdx.x;
  const int pl = tid & 15;              // p lane
  const int tg = tid >> 4;              // t group
  __shared__ float Gsr[16 * 65], Gsi[16 * 65], Tc[16 * 65], Tsn[16 * 65];
  float acc[4][4];
  const float bv = bias[r & 7];
  #pragma unroll
  for (int kt = 0; kt < 4; ++kt)
    #pragma unroll
    for (int kp = 0; kp < 4; ++kp) acc[kt][kp] = bv;
  for (int jk = 0; jk < MJ; jk += 16) {
    __syncthreads();
    for (int idx = tid; idx < 16 * 64; idx += 256) {
      int jj = idx >> 6, c = idx & 63;
      Gsr[jj * 65 + c] = Gr[((size_t)(jk + jj) * 128 + r) * T_ + t0 + c];
      Gsi[jj * 65 + c] = Gi[((size_t)(jk + jj) * 128 + r) * T_ + t0 + c];
      int p = p0 + c;
      Tc[jj * 65 + c]  = (p < P_) ? Ct[(jk + jj) * P_ + p] : 0.f;
      Tsn[jj * 65 + c] = (p < P_) ? St[(jk + jj) * P_ + p] : 0.f;
    }
    __syncthreads();
    for (int jj = 0; jj < 16; ++jj) {
      float gr[4], gi[4], cv[4], sv[4];
      #pragma unroll
      for (int kt = 0; kt < 4; ++kt) {
        gr[kt] = Gsr[jj * 65 + kt * 16 + tg];
        gi[kt] = Gsi[jj * 65 + kt * 16 + tg];
      }
      #pragma unroll
      for (int kp = 0; kp < 4; ++kp) {
        cv[kp] = Tc[jj * 65 + kp * 16 + pl];
        sv[kp] = Tsn[jj * 65 + kp * 16 + pl];
      }
      #pragma unroll
      for (int kt = 0; kt < 4; ++kt)
        #pragma unroll
        for (int kp = 0; kp < 4; ++kp) {
          acc[kt][kp] = fmaf(gr[kt],  cv[kp], acc[kt][kp]);
          acc[kt][kp] = fmaf(gi[kt], -sv[kp], acc[kt][kp]);
        }
    }
  }
  #pragma unroll
  for (int kt = 0; kt < 4; ++kt) {
    int t = t0 + kt * 16 + tg;
    #pragma unroll
    for (int kp = 0; kp < 4; ++kp) {
      int p = p0 + kp * 16 + pl;
      if (p < P_) out[((size_t)r * T_ + t) * P_ + p] = acc[kt][kp];
    }
  }
}

extern "C" void kernel_launch(void* const* d_in, const int* in_sizes, int n_in,
                              void* d_out, int out_size, void* d_ws, size_t ws_size,
                              hipStream_t stream) {
  const float* x    = (const float*)d_in[0];
  const float* w    = (const float*)d_in[1];
  const float* bias = (const float*)d_in[2];
  const float* Psyn = (const float*)d_in[3];
  const float* Pinv = (const float*)d_in[4];
  float* out = (float*)d_out;

  float* ws = (float*)d_ws;
  float* Ctab = ws;                              // 64*255
  float* Stab = Ctab + MJ * P_;
  float* Xr   = Stab + MJ * P_;                  // [64][192][128]
  float* Xi   = Xr + (size_t)MJ * RT * T_;
  float* XLr  = Xi + (size_t)MJ * RT * T_;       // [64][128][192]
  float* XLi  = XLr + (size_t)MJ * L_ * RT;
  float* OLr  = Xr;                              // reuse (X dead): [64][128][128]
  float* OLi  = Xi;
  float* Gr2  = XLr;                             // reuse (XL dead): [64][128][128]
  float* Gi2  = XLi;

  k_tables<<<(MJ * P_ + 255) / 256, 256, 0, stream>>>(Ctab, Stab);
  k_dft<<<dim3(RT, 4), 256, 0, stream>>>(x, w, Ctab, Stab, Xr, Xi);
  k_leg_fwd<<<dim3(MJ, 12), 256, 0, stream>>>(Xr, Xi, Pinv, XLr, XLi);
  k_hprod<<<dim3(MJ, 16), 256, 0, stream>>>(XLr, XLi, OLr, OLi);
  k_leg_inv<<<dim3(MJ, 8), 256, 0, stream>>>(OLr, OLi, Psyn, Gr2, Gi2);
  k_idft<<<dim3(128, 8), 256, 0, stream>>>(Gr2, Gi2, Ctab, Stab, bias, out);
}

// Round 3
// 181.043 us; speedup vs baseline: 1.7739x; 1.2707x over previous
//
#include <hip/hip_runtime.h>

#define PI_ 3.14159265358979323846

typedef __attribute__((ext_vector_type(8))) short bf16x8;
typedef __attribute__((ext_vector_type(4))) float f32x4;
typedef __attribute__((ext_vector_type(8))) unsigned short u16x8;
typedef unsigned short u16;

// f32 -> bf16 round-to-nearest-even, manual (no lib dependency)
__device__ inline u16 f2bf(float f) {
  unsigned u = __float_as_uint(f);
  unsigned r = (u + 0x7FFFu + ((u >> 16) & 1u)) >> 16;
  return (u16)r;
}
__device__ inline float bf2f(u16 h) { return __uint_as_float(((unsigned)h) << 16); }
__device__ inline void splitf(float v, u16& h, u16& l) {
  h = f2bf(v);
  l = f2bf(v - bf2f(h));
}

// ============ tables ============
// B1t: [n=128][p=256], n=2j+kind; val = (kind ? -sin : cos)(2pi*2j*p/255)/255; p=255 -> 0
__global__ void k_tab1(u16* __restrict__ B1h, u16* __restrict__ B1l) {
  int idx = blockIdx.x * 256 + threadIdx.x;
  if (idx >= 128 * 256) return;
  int n = idx >> 8, p = idx & 255;
  int j = n >> 1, kind = n & 1;
  double ang = (2.0 * PI_ / 255.0) * (double)(2 * j) * (double)p;
  double v = (p < 255) ? (kind ? -sin(ang) : cos(ang)) * (1.0 / 255.0) : 0.0;
  u16 h, l; splitf((float)v, h, l);
  B1h[idx] = h; B1l[idx] = l;
}
// B5t: [p=256][k=128], k=2j+kind; val = scale_j * (kind ? -sin : cos)(2pi*2j*p/255)
__global__ void k_tab2(u16* __restrict__ B5h, u16* __restrict__ B5l) {
  int idx = blockIdx.x * 256 + threadIdx.x;
  if (idx >= 256 * 128) return;
  int p = idx >> 7, k = idx & 127;
  int j = k >> 1, kind = k & 1;
  double ang = (2.0 * PI_ / 255.0) * (double)(2 * j) * (double)p;
  double sc = (j == 0) ? 1.0 : 2.0;
  double v = (p < 255) ? sc * (kind ? -sin(ang) : cos(ang)) : 0.0;
  u16 h, l; splitf((float)v, h, l);
  B5h[idx] = h; B5l[idx] = l;
}

#define MFMA __builtin_amdgcn_mfma_f32_16x16x32_bf16

// ============ S1: forward DFT: C[u][n] = sum_p in[u][p] * B1[p][n] ============
// u<16384: x rows (r'=u>>7, t=u&127); u>=16384: w rows. Out: X planes [j][kind][r'(192)][t]
__global__ __launch_bounds__(256) void k_s1(
    const float* __restrict__ x, const float* __restrict__ w,
    const u16* __restrict__ B1h, const u16* __restrict__ B1l,
    u16* __restrict__ Xh, u16* __restrict__ Xl) {
  const int u0 = blockIdx.x * 64;
  const int n0 = blockIdx.y * 64;
  const int tid = threadIdx.x;
  const int sr = tid >> 2, sc = tid & 3;
  const int lane = tid & 63, wid = tid >> 6;
  const int wm = wid & 1, wn = wid >> 1;
  const int frow = lane & 15, fkg = lane >> 4;
  __shared__ u16 lds[4][2560];
  f32x4 acc[2][2] = {};
  const int u = u0 + sr;
  const float* src = (u < 16384) ? (x + (size_t)u * 255)
                                 : (w + (size_t)(u - 16384) * 255);
  for (int k0 = 0; k0 < 256; k0 += 32) {
    __syncthreads();
    { // stage A (f32, stride-255 rows -> scalar loads with pad guard)
      int kb = k0 + sc * 8;
      bf16x8 hv, lv;
      #pragma unroll
      for (int i = 0; i < 8; ++i) {
        int k = kb + i;
        float v = (k < 255) ? src[k] : 0.f;
        u16 h, l; splitf(v, h, l);
        hv[i] = (short)h; lv[i] = (short)l;
      }
      *reinterpret_cast<bf16x8*>(&lds[0][sr * 40 + sc * 8]) = hv;
      *reinterpret_cast<bf16x8*>(&lds[1][sr * 40 + sc * 8]) = lv;
    }
    { // stage B (pre-split u16 table [n][256])
      size_t o = (size_t)(n0 + sr) * 256 + k0 + sc * 8;
      *reinterpret_cast<bf16x8*>(&lds[2][sr * 40 + sc * 8]) =
          *reinterpret_cast<const bf16x8*>(&B1h[o]);
      *reinterpret_cast<bf16x8*>(&lds[3][sr * 40 + sc * 8]) =
          *reinterpret_cast<const bf16x8*>(&B1l[o]);
    }
    __syncthreads();
    bf16x8 ah[2], al[2], bh[2], bl[2];
    #pragma unroll
    for (int fm = 0; fm < 2; ++fm) {
      int ar = wm * 32 + fm * 16 + frow;
      ah[fm] = *reinterpret_cast<const bf16x8*>(&lds[0][ar * 40 + fkg * 8]);
      al[fm] = *reinterpret_cast<const bf16x8*>(&lds[1][ar * 40 + fkg * 8]);
    }
    #pragma unroll
    for (int fn = 0; fn < 2; ++fn) {
      int br = wn * 32 + fn * 16 + frow;
      bh[fn] = *reinterpret_cast<const bf16x8*>(&lds[2][br * 40 + fkg * 8]);
      bl[fn] = *reinterpret_cast<const bf16x8*>(&lds[3][br * 40 + fkg * 8]);
    }
    #pragma unroll
    for (int fn = 0; fn < 2; ++fn)
      #pragma unroll
      for (int fm = 0; fm < 2; ++fm) {
        acc[fm][fn] = MFMA(ah[fm], bh[fn], acc[fm][fn], 0, 0, 0);
        acc[fm][fn] = MFMA(ah[fm], bl[fn], acc[fm][fn], 0, 0, 0);
        acc[fm][fn] = MFMA(al[fm], bh[fn], acc[fm][fn], 0, 0, 0);
      }
  }
  #pragma unroll
  for (int fm = 0; fm < 2; ++fm)
    #pragma unroll
    for (int fn = 0; fn < 2; ++fn) {
      int gm = u0 + wm * 32 + fm * 16 + fkg * 4;
      int gn = n0 + wn * 32 + fn * 16 + frow;
      int j = gn >> 1, kind = gn & 1;
      int rp = (gm < 16384) ? (gm >> 7) : (128 + ((gm - 16384) >> 7));
      int tb = gm & 127;
      u16 h[4], l[4];
      #pragma unroll
      for (int r = 0; r < 4; ++r) splitf(acc[fm][fn][r], h[r], l[r]);
      size_t o = ((size_t)(j * 2 + kind) * 192 + rp) * 128 + tb;
      *reinterpret_cast<ushort4*>(&Xh[o]) = make_ushort4(h[0], h[1], h[2], h[3]);
      *reinterpret_cast<ushort4*>(&Xl[o]) = make_ushort4(l[0], l[1], l[2], l[3]);
    }
}

// ============ S2: Legendre analysis per j: C[l][n2] = sum_t Pinv[m][l][t] * X[j][n2][t]
// n2 = kind*192 + r'. Out: XL planes [j][kind][r'(192)][l]
__global__ __launch_bounds__(256) void k_s2(
    const u16* __restrict__ Xh, const u16* __restrict__ Xl,
    const float* __restrict__ Pinv,
    u16* __restrict__ XLh, u16* __restrict__ XLl) {
  const int j = blockIdx.x;
  const int l0 = (blockIdx.y & 1) * 64;
  const int nt = blockIdx.y >> 1;            // 0..5
  const int kind = (nt >= 3) ? 1 : 0;
  const int rp0 = (nt - 3 * kind) * 64;
  const int tid = threadIdx.x;
  const int sr = tid >> 2, sc = tid & 3;
  const int lane = tid & 63, wid = tid >> 6;
  const int wm = wid & 1, wn = wid >> 1;
  const int frow = lane & 15, fkg = lane >> 4;
  __shared__ u16 lds[4][2560];
  f32x4 acc[2][2] = {};
  const int m = 127 + 2 * j;
  const float* asrc = Pinv + ((size_t)m * 128 + l0 + sr) * 128;
  const u16* bbase_h = Xh + ((size_t)(j * 2 + kind) * 192 + rp0 + sr) * 128;
  const u16* bbase_l = Xl + ((size_t)(j * 2 + kind) * 192 + rp0 + sr) * 128;
  for (int k0 = 0; k0 < 128; k0 += 32) {
    __syncthreads();
    { // stage A: Pinv f32 -> split
      const float4* ap = reinterpret_cast<const float4*>(asrc + k0 + sc * 8);
      float4 v0 = ap[0], v1 = ap[1];
      float vv[8] = {v0.x, v0.y, v0.z, v0.w, v1.x, v1.y, v1.z, v1.w};
      bf16x8 hv, lv;
      #pragma unroll
      for (int i = 0; i < 8; ++i) { u16 h, l; splitf(vv[i], h, l); hv[i] = (short)h; lv[i] = (short)l; }
      *reinterpret_cast<bf16x8*>(&lds[0][sr * 40 + sc * 8]) = hv;
      *reinterpret_cast<bf16x8*>(&lds[1][sr * 40 + sc * 8]) = lv;
    }
    { // stage B: pre-split X
      *reinterpret_cast<bf16x8*>(&lds[2][sr * 40 + sc * 8]) =
          *reinterpret_cast<const bf16x8*>(&bbase_h[k0 + sc * 8]);
      *reinterpret_cast<bf16x8*>(&lds[3][sr * 40 + sc * 8]) =
          *reinterpret_cast<const bf16x8*>(&bbase_l[k0 + sc * 8]);
    }
    __syncthreads();
    bf16x8 ah[2], al[2], bh[2], bl[2];
    #pragma unroll
    for (int fm = 0; fm < 2; ++fm) {
      int ar = wm * 32 + fm * 16 + frow;
      ah[fm] = *reinterpret_cast<const bf16x8*>(&lds[0][ar * 40 + fkg * 8]);
      al[fm] = *reinterpret_cast<const bf16x8*>(&lds[1][ar * 40 + fkg * 8]);
    }
    #pragma unroll
    for (int fn = 0; fn < 2; ++fn) {
      int br = wn * 32 + fn * 16 + frow;
      bh[fn] = *reinterpret_cast<const bf16x8*>(&lds[2][br * 40 + fkg * 8]);
      bl[fn] = *reinterpret_cast<const bf16x8*>(&lds[3][br * 40 + fkg * 8]);
    }
    #pragma unroll
    for (int fn = 0; fn < 2; ++fn)
      #pragma unroll
      for (int fm = 0; fm < 2; ++fm) {
        acc[fm][fn] = MFMA(ah[fm], bh[fn], acc[fm][fn], 0, 0, 0);
        acc[fm][fn] = MFMA(ah[fm], bl[fn], acc[fm][fn], 0, 0, 0);
        acc[fm][fn] = MFMA(al[fm], bh[fn], acc[fm][fn], 0, 0, 0);
      }
  }
  #pragma unroll
  for (int fm = 0; fm < 2; ++fm)
    #pragma unroll
    for (int fn = 0; fn < 2; ++fn) {
      int l = l0 + wm * 32 + fm * 16 + fkg * 4;
      int rp = rp0 + wn * 32 + fn * 16 + frow;
      u16 h[4], lo[4];
      #pragma unroll
      for (int r = 0; r < 4; ++r) splitf(acc[fm][fn][r], h[r], lo[r]);
      size_t o = ((size_t)(j * 2 + kind) * 192 + rp) * 128 + l;
      *reinterpret_cast<ushort4*>(&XLh[o]) = make_ushort4(h[0], h[1], h[2], h[3]);
      *reinterpret_cast<ushort4*>(&XLl[o]) = make_ushort4(lo[0], lo[1], lo[2], lo[3]);
    }
}

// ============ S3: harmonic product (VALU): OL[j][kind][bo][l] ============
__global__ __launch_bounds__(256) void k_s3(
    const u16* __restrict__ XLh, const u16* __restrict__ XLl,
    u16* __restrict__ OLh, u16* __restrict__ OLl) {
  const int j = blockIdx.x;
  const int l0 = blockIdx.y * 16;
  const int tid = threadIdx.x;
  __shared__ float Xs[2][128][17];
  __shared__ float Ws[2][64][17];
  for (int idx = tid; idx < 2 * 192 * 16; idx += 256) {
    int kind = idx / (192 * 16);
    int rem = idx - kind * (192 * 16);
    int rp = rem >> 4, lc = rem & 15;
    size_t src = ((size_t)(j * 2 + kind) * 192 + rp) * 128 + l0 + lc;
    float v = bf2f(XLh[src]) + bf2f(XLl[src]);
    if (rp < 128) Xs[kind][rp][lc] = v; else Ws[kind][rp - 128][lc] = v;
  }
  __syncthreads();
  const int bo = tid & 127, lg = tid >> 7;
  const int b = bo >> 3, o = bo & 7;
  u16 hr[8], lr[8], hi[8], li[8];
  #pragma unroll
  for (int i2 = 0; i2 < 8; ++i2) {
    int lc = lg * 8 + i2;
    float ar = 0.f, ai = 0.f;
    #pragma unroll
    for (int i = 0; i < 8; ++i) {
      float xr = Xs[0][b * 8 + i][lc], xi = Xs[1][b * 8 + i][lc];
      float wr = Ws[0][o * 8 + i][lc], wi = Ws[1][o * 8 + i][lc];
      ar += xr * wr - xi * wi;
      ai += xr * wi + xi * wr;
    }
    splitf(ar, hr[i2], lr[i2]);
    splitf(ai, hi[i2], li[i2]);
  }
  size_t o0 = ((size_t)(j * 2 + 0) * 128 + bo) * 128 + l0 + lg * 8;
  size_t o1 = ((size_t)(j * 2 + 1) * 128 + bo) * 128 + l0 + lg * 8;
  u16x8 v;
  #pragma unroll
  for (int i = 0; i < 8; ++i) v[i] = hr[i];
  *reinterpret_cast<u16x8*>(&OLh[o0]) = v;
  #pragma unroll
  for (int i = 0; i < 8; ++i) v[i] = lr[i];
  *reinterpret_cast<u16x8*>(&OLl[o0]) = v;
  #pragma unroll
  for (int i = 0; i < 8; ++i) v[i] = hi[i];
  *reinterpret_cast<u16x8*>(&OLh[o1]) = v;
  #pragma unroll
  for (int i = 0; i < 8; ++i) v[i] = li[i];
  *reinterpret_cast<u16x8*>(&OLl[o1]) = v;
}

// ============ S4: Legendre synthesis per j: C[t][n4] = sum_l Psyn[m][t][l] * OL[j][n4][l]
// n4 = kind*128 + bo. Out: G planes [u5=(bo*128+t)][k5=2j+kind]
__global__ __launch_bounds__(256) void k_s4(
    const u16* __restrict__ OLh, const u16* __restrict__ OLl,
    const float* __restrict__ Psyn,
    u16* __restrict__ Gh, u16* __restrict__ Gl) {
  const int j = blockIdx.x;
  const int t0 = (blockIdx.y & 1) * 64;
  const int nt = blockIdx.y >> 1;           // 0..3
  const int kind = nt >> 1;
  const int bo0 = (nt & 1) * 64;
  const int tid = threadIdx.x;
  const int sr = tid >> 2, sc = tid & 3;
  const int lane = tid & 63, wid = tid >> 6;
  const int wm = wid & 1, wn = wid >> 1;
  const int frow = lane & 15, fkg = lane >> 4;
  __shared__ u16 lds[4][2560];
  f32x4 acc[2][2] = {};
  const int m = 127 + 2 * j;
  const float* asrc = Psyn + ((size_t)m * 128 + t0 + sr) * 128;
  const u16* bbase_h = OLh + ((size_t)(j * 2 + kind) * 128 + bo0 + sr) * 128;
  const u16* bbase_l = OLl + ((size_t)(j * 2 + kind) * 128 + bo0 + sr) * 128;
  for (int k0 = 0; k0 < 128; k0 += 32) {
    __syncthreads();
    {
      const float4* ap = reinterpret_cast<const float4*>(asrc + k0 + sc * 8);
      float4 v0 = ap[0], v1 = ap[1];
      float vv[8] = {v0.x, v0.y, v0.z, v0.w, v1.x, v1.y, v1.z, v1.w};
      bf16x8 hv, lv;
      #pragma unroll
      for (int i = 0; i < 8; ++i) { u16 h, l; splitf(vv[i], h, l); hv[i] = (short)h; lv[i] = (short)l; }
      *reinterpret_cast<bf16x8*>(&lds[0][sr * 40 + sc * 8]) = hv;
      *reinterpret_cast<bf16x8*>(&lds[1][sr * 40 + sc * 8]) = lv;
    }
    {
      *reinterpret_cast<bf16x8*>(&lds[2][sr * 40 + sc * 8]) =
          *reinterpret_cast<const bf16x8*>(&bbase_h[k0 + sc * 8]);
      *reinterpret_cast<bf16x8*>(&lds[3][sr * 40 + sc * 8]) =
          *reinterpret_cast<const bf16x8*>(&bbase_l[k0 + sc * 8]);
    }
    __syncthreads();
    bf16x8 ah[2], al[2], bh[2], bl[2];
    #pragma unroll
    for (int fm = 0; fm < 2; ++fm) {
      int ar = wm * 32 + fm * 16 + frow;
      ah[fm] = *reinterpret_cast<const bf16x8*>(&lds[0][ar * 40 + fkg * 8]);
      al[fm] = *reinterpret_cast<const bf16x8*>(&lds[1][ar * 40 + fkg * 8]);
    }
    #pragma unroll
    for (int fn = 0; fn < 2; ++fn) {
      int br = wn * 32 + fn * 16 + frow;
      bh[fn] = *reinterpret_cast<const bf16x8*>(&lds[2][br * 40 + fkg * 8]);
      bl[fn] = *reinterpret_cast<const bf16x8*>(&lds[3][br * 40 + fkg * 8]);
    }
    #pragma unroll
    for (int fn = 0; fn < 2; ++fn)
      #pragma unroll
      for (int fm = 0; fm < 2; ++fm) {
        acc[fm][fn] = MFMA(ah[fm], bh[fn], acc[fm][fn], 0, 0, 0);
        acc[fm][fn] = MFMA(ah[fm], bl[fn], acc[fm][fn], 0, 0, 0);
        acc[fm][fn] = MFMA(al[fm], bh[fn], acc[fm][fn], 0, 0, 0);
      }
  }
  #pragma unroll
  for (int fm = 0; fm < 2; ++fm)
    #pragma unroll
    for (int fn = 0; fn < 2; ++fn) {
      int tt = t0 + wm * 32 + fm * 16 + fkg * 4;
      int bo = bo0 + wn * 32 + fn * 16 + frow;
      #pragma unroll
      for (int r = 0; r < 4; ++r) {
        u16 h, l; splitf(acc[fm][fn][r], h, l);
        size_t o = ((size_t)bo * 128 + tt + r) * 128 + 2 * j + kind;
        Gh[o] = h; Gl[o] = l;
      }
    }
}

// ============ S5: inverse DFT: out[u5][p] = sum_k5 G[u5][k5] * B5[k5][p] + bias
__global__ __launch_bounds__(256) void k_s5(
    const u16* __restrict__ Gh, const u16* __restrict__ Gl,
    const u16* __restrict__ B5h, const u16* __restrict__ B5l,
    const float* __restrict__ bias, float* __restrict__ out) {
  const int u0 = blockIdx.x * 64;
  const int p0 = blockIdx.y * 64;
  const int tid = threadIdx.x;
  const int sr = tid >> 2, sc = tid & 3;
  const int lane = tid & 63, wid = tid >> 6;
  const int wm = wid & 1, wn = wid >> 1;
  const int frow = lane & 15, fkg = lane >> 4;
  __shared__ u16 lds[4][2560];
  f32x4 acc[2][2] = {};
  const u16* abase_h = Gh + (size_t)(u0 + sr) * 128;
  const u16* abase_l = Gl + (size_t)(u0 + sr) * 128;
  const u16* bbase_h = B5h + (size_t)(p0 + sr) * 128;
  const u16* bbase_l = B5l + (size_t)(p0 + sr) * 128;
  for (int k0 = 0; k0 < 128; k0 += 32) {
    __syncthreads();
    *reinterpret_cast<bf16x8*>(&lds[0][sr * 40 + sc * 8]) =
        *reinterpret_cast<const bf16x8*>(&abase_h[k0 + sc * 8]);
    *reinterpret_cast<bf16x8*>(&lds[1][sr * 40 + sc * 8]) =
        *reinterpret_cast<const bf16x8*>(&abase_l[k0 + sc * 8]);
    *reinterpret_cast<bf16x8*>(&lds[2][sr * 40 + sc * 8]) =
        *reinterpret_cast<const bf16x8*>(&bbase_h[k0 + sc * 8]);
    *reinterpret_cast<bf16x8*>(&lds[3][sr * 40 + sc * 8]) =
        *reinterpret_cast<const bf16x8*>(&bbase_l[k0 + sc * 8]);
    __syncthreads();
    bf16x8 ah[2], al[2], bh[2], bl[2];
    #pragma unroll
    for (int fm = 0; fm < 2; ++fm) {
      int ar = wm * 32 + fm * 16 + frow;
      ah[fm] = *reinterpret_cast<const bf16x8*>(&lds[0][ar * 40 + fkg * 8]);
      al[fm] = *reinterpret_cast<const bf16x8*>(&lds[1][ar * 40 + fkg * 8]);
    }
    #pragma unroll
    for (int fn = 0; fn < 2; ++fn) {
      int br = wn * 32 + fn * 16 + frow;
      bh[fn] = *reinterpret_cast<const bf16x8*>(&lds[2][br * 40 + fkg * 8]);
      bl[fn] = *reinterpret_cast<const bf16x8*>(&lds[3][br * 40 + fkg * 8]);
    }
    #pragma unroll
    for (int fn = 0; fn < 2; ++fn)
      #pragma unroll
      for (int fm = 0; fm < 2; ++fm) {
        acc[fm][fn] = MFMA(ah[fm], bh[fn], acc[fm][fn], 0, 0, 0);
        acc[fm][fn] = MFMA(ah[fm], bl[fn], acc[fm][fn], 0, 0, 0);
        acc[fm][fn] = MFMA(al[fm], bh[fn], acc[fm][fn], 0, 0, 0);
      }
  }
  const int bo = u0 >> 7;
  const float bv = bias[bo & 7];
  #pragma unroll
  for (int fm = 0; fm < 2; ++fm)
    #pragma unroll
    for (int fn = 0; fn < 2; ++fn) {
      int u5 = u0 + wm * 32 + fm * 16 + fkg * 4;
      int p = p0 + wn * 32 + fn * 16 + frow;
      int t = u5 & 127;
      if (p < 255) {
        #pragma unroll
        for (int r = 0; r < 4; ++r)
          out[((size_t)bo * 128 + t + r) * 255 + p] = acc[fm][fn][r] + bv;
      }
    }
}

extern "C" void kernel_launch(void* const* d_in, const int* in_sizes, int n_in,
                              void* d_out, int out_size, void* d_ws, size_t ws_size,
                              hipStream_t stream) {
  const float* x    = (const float*)d_in[0];
  const float* w    = (const float*)d_in[1];
  const float* bias = (const float*)d_in[2];
  const float* Psyn = (const float*)d_in[3];
  const float* Pinv = (const float*)d_in[4];
  float* out = (float*)d_out;

  u16* ws = (u16*)d_ws;
  const size_t PLX = 3145728;   // 64*2*192*128
  u16* Xh  = ws;
  u16* Xl  = ws + PLX;
  u16* XLh = ws + 2 * PLX;
  u16* XLl = ws + 3 * PLX;
  // B1 lives in the (not-yet-written) XL region; consumed by S1 before S2 writes XL.
  u16* B1h = XLh;
  u16* B1l = XLh + 32768;
  // OL reuses X region head (X dead after S2); B5 goes in X region tail.
  u16* OLh = Xh;
  u16* OLl = Xl;
  u16* B5h = Xh + 2097152;
  u16* B5l = Xl + 2097152;
  // G reuses XL region head (XL dead after S3).
  u16* Gh = XLh;
  u16* Gl = XLl;

  k_tab1<<<128, 256, 0, stream>>>(B1h, B1l);
  k_s1<<<dim3(384, 2), 256, 0, stream>>>(x, w, B1h, B1l, Xh, Xl);
  k_s2<<<dim3(64, 12), 256, 0, stream>>>(Xh, Xl, Pinv, XLh, XLl);
  k_tab2<<<128, 256, 0, stream>>>(B5h, B5l);
  k_s3<<<dim3(64, 8), 256, 0, stream>>>(XLh, XLl, OLh, OLl);
  k_s4<<<dim3(64, 8), 256, 0, stream>>>(OLh, OLl, Psyn, Gh, Gl);
  k_s5<<<dim3(256, 4), 256, 0, stream>>>(Gh, Gl, B5h, B5l, bias, out);
}

// Round 7
// 158.159 us; speedup vs baseline: 2.0305x; 1.1447x over previous
//
#include <hip/hip_runtime.h>

#define PI_ 3.14159265358979323846

typedef __attribute__((ext_vector_type(8))) short bf16x8;
typedef __attribute__((ext_vector_type(4))) float f32x4;
typedef __attribute__((ext_vector_type(8))) unsigned short u16x8;
typedef unsigned short u16;

// f32 -> bf16 round-to-nearest-even, manual (no lib dependency)
__device__ inline u16 f2bf(float f) {
  unsigned u = __float_as_uint(f);
  unsigned r = (u + 0x7FFFu + ((u >> 16) & 1u)) >> 16;
  return (u16)r;
}
__device__ inline float bf2f(u16 h) { return __uint_as_float(((unsigned)h) << 16); }
__device__ inline void splitf(float v, u16& h, u16& l) {
  h = f2bf(v);
  l = f2bf(v - bf2f(h));
}

// ============ tables (fused; DEDICATED ws region — no aliasing) ============
// B1t: [n=128][p=256], n=2j+kind; val = (kind ? -sin : cos)(2pi*2j*p/255)/255; p=255 -> 0
// B5t: [p=256][k=128], k=2j+kind; val = scale_j * (kind ? -sin : cos)(2pi*2j*p/255)
__global__ void k_tab(u16* __restrict__ B1h, u16* __restrict__ B1l,
                      u16* __restrict__ B5h, u16* __restrict__ B5l) {
  int idx = blockIdx.x * 256 + threadIdx.x;
  if (idx < 128 * 256) {
    int n = idx >> 8, p = idx & 255;
    int j = n >> 1, kind = n & 1;
    double ang = (2.0 * PI_ / 255.0) * (double)(2 * j) * (double)p;
    double v = (p < 255) ? (kind ? -sin(ang) : cos(ang)) * (1.0 / 255.0) : 0.0;
    u16 h, l; splitf((float)v, h, l);
    B1h[idx] = h; B1l[idx] = l;
  } else {
    int i2 = idx - 128 * 256;
    if (i2 >= 256 * 128) return;
    int p = i2 >> 7, k = i2 & 127;
    int j = k >> 1, kind = k & 1;
    double ang = (2.0 * PI_ / 255.0) * (double)(2 * j) * (double)p;
    double sc = (j == 0) ? 1.0 : 2.0;
    double v = (p < 255) ? sc * (kind ? -sin(ang) : cos(ang)) : 0.0;
    u16 h, l; splitf((float)v, h, l);
    B5h[i2] = h; B5l[i2] = l;
  }
}

#define MFMA __builtin_amdgcn_mfma_f32_16x16x32_bf16

// ============ S1: forward DFT: C[u][n] = sum_p in[u][p] * B1[p][n] ============
// u<16384: x rows (r'=u>>7, t=u&127); u>=16384: w rows. Out: X planes [j][kind][r'(192)][t]
__global__ __launch_bounds__(256) void k_s1(
    const float* __restrict__ x, const float* __restrict__ w,
    const u16* __restrict__ B1h, const u16* __restrict__ B1l,
    u16* __restrict__ Xh, u16* __restrict__ Xl) {
  const int u0 = blockIdx.x * 64;
  const int n0 = blockIdx.y * 64;
  const int tid = threadIdx.x;
  const int sr = tid >> 2, sc = tid & 3;
  const int lane = tid & 63, wid = tid >> 6;
  const int wm = wid & 1, wn = wid >> 1;
  const int frow = lane & 15, fkg = lane >> 4;
  __shared__ u16 lds[4][2560];
  f32x4 acc[2][2] = {};
  const int u = u0 + sr;
  const float* src = (u < 16384) ? (x + (size_t)u * 255)
                                 : (w + (size_t)(u - 16384) * 255);
  for (int k0 = 0; k0 < 256; k0 += 32) {
    __syncthreads();
    { // stage A (f32, stride-255 rows -> scalar loads with pad guard)
      int kb = k0 + sc * 8;
      bf16x8 hv, lv;
      #pragma unroll
      for (int i = 0; i < 8; ++i) {
        int k = kb + i;
        float v = (k < 255) ? src[k] : 0.f;
        u16 h, l; splitf(v, h, l);
        hv[i] = (short)h; lv[i] = (short)l;
      }
      *reinterpret_cast<bf16x8*>(&lds[0][sr * 40 + sc * 8]) = hv;
      *reinterpret_cast<bf16x8*>(&lds[1][sr * 40 + sc * 8]) = lv;
    }
    { // stage B (pre-split u16 table [n][256])
      size_t o = (size_t)(n0 + sr) * 256 + k0 + sc * 8;
      *reinterpret_cast<bf16x8*>(&lds[2][sr * 40 + sc * 8]) =
          *reinterpret_cast<const bf16x8*>(&B1h[o]);
      *reinterpret_cast<bf16x8*>(&lds[3][sr * 40 + sc * 8]) =
          *reinterpret_cast<const bf16x8*>(&B1l[o]);
    }
    __syncthreads();
    bf16x8 ah[2], al[2], bh[2], bl[2];
    #pragma unroll
    for (int fm = 0; fm < 2; ++fm) {
      int ar = wm * 32 + fm * 16 + frow;
      ah[fm] = *reinterpret_cast<const bf16x8*>(&lds[0][ar * 40 + fkg * 8]);
      al[fm] = *reinterpret_cast<const bf16x8*>(&lds[1][ar * 40 + fkg * 8]);
    }
    #pragma unroll
    for (int fn = 0; fn < 2; ++fn) {
      int br = wn * 32 + fn * 16 + frow;
      bh[fn] = *reinterpret_cast<const bf16x8*>(&lds[2][br * 40 + fkg * 8]);
      bl[fn] = *reinterpret_cast<const bf16x8*>(&lds[3][br * 40 + fkg * 8]);
    }
    #pragma unroll
    for (int fn = 0; fn < 2; ++fn)
      #pragma unroll
      for (int fm = 0; fm < 2; ++fm) {
        acc[fm][fn] = MFMA(ah[fm], bh[fn], acc[fm][fn], 0, 0, 0);
        acc[fm][fn] = MFMA(ah[fm], bl[fn], acc[fm][fn], 0, 0, 0);
        acc[fm][fn] = MFMA(al[fm], bh[fn], acc[fm][fn], 0, 0, 0);
      }
  }
  #pragma unroll
  for (int fm = 0; fm < 2; ++fm)
    #pragma unroll
    for (int fn = 0; fn < 2; ++fn) {
      int gm = u0 + wm * 32 + fm * 16 + fkg * 4;
      int gn = n0 + wn * 32 + fn * 16 + frow;
      int j = gn >> 1, kind = gn & 1;
      int rp = (gm < 16384) ? (gm >> 7) : (128 + ((gm - 16384) >> 7));
      int tb = gm & 127;
      u16 h[4], l[4];
      #pragma unroll
      for (int r = 0; r < 4; ++r) splitf(acc[fm][fn][r], h[r], l[r]);
      size_t o = ((size_t)(j * 2 + kind) * 192 + rp) * 128 + tb;
      *reinterpret_cast<ushort4*>(&Xh[o]) = make_ushort4(h[0], h[1], h[2], h[3]);
      *reinterpret_cast<ushort4*>(&Xl[o]) = make_ushort4(l[0], l[1], l[2], l[3]);
    }
}

// ============ S2: Legendre analysis per j: C[l][n2] = sum_t Pinv[m][l][t] * X[j][n2][t]
// n2 = kind*192 + r'. Out: XL planes [j][kind][r'(192)][l]
__global__ __launch_bounds__(256) void k_s2(
    const u16* __restrict__ Xh, const u16* __restrict__ Xl,
    const float* __restrict__ Pinv,
    u16* __restrict__ XLh, u16* __restrict__ XLl) {
  const int j = blockIdx.x;
  const int l0 = (blockIdx.y & 1) * 64;
  const int nt = blockIdx.y >> 1;            // 0..5
  const int kind = (nt >= 3) ? 1 : 0;
  const int rp0 = (nt - 3 * kind) * 64;
  const int tid = threadIdx.x;
  const int sr = tid >> 2, sc = tid & 3;
  const int lane = tid & 63, wid = tid >> 6;
  const int wm = wid & 1, wn = wid >> 1;
  const int frow = lane & 15, fkg = lane >> 4;
  __shared__ u16 lds[4][2560];
  f32x4 acc[2][2] = {};
  const int m = 127 + 2 * j;
  const float* asrc = Pinv + ((size_t)m * 128 + l0 + sr) * 128;
  const u16* bbase_h = Xh + ((size_t)(j * 2 + kind) * 192 + rp0 + sr) * 128;
  const u16* bbase_l = Xl + ((size_t)(j * 2 + kind) * 192 + rp0 + sr) * 128;
  for (int k0 = 0; k0 < 128; k0 += 32) {
    __syncthreads();
    { // stage A: Pinv f32 -> split
      const float4* ap = reinterpret_cast<const float4*>(asrc + k0 + sc * 8);
      float4 v0 = ap[0], v1 = ap[1];
      float vv[8] = {v0.x, v0.y, v0.z, v0.w, v1.x, v1.y, v1.z, v1.w};
      bf16x8 hv, lv;
      #pragma unroll
      for (int i = 0; i < 8; ++i) { u16 h, l; splitf(vv[i], h, l); hv[i] = (short)h; lv[i] = (short)l; }
      *reinterpret_cast<bf16x8*>(&lds[0][sr * 40 + sc * 8]) = hv;
      *reinterpret_cast<bf16x8*>(&lds[1][sr * 40 + sc * 8]) = lv;
    }
    { // stage B: pre-split X
      *reinterpret_cast<bf16x8*>(&lds[2][sr * 40 + sc * 8]) =
          *reinterpret_cast<const bf16x8*>(&bbase_h[k0 + sc * 8]);
      *reinterpret_cast<bf16x8*>(&lds[3][sr * 40 + sc * 8]) =
          *reinterpret_cast<const bf16x8*>(&bbase_l[k0 + sc * 8]);
    }
    __syncthreads();
    bf16x8 ah[2], al[2], bh[2], bl[2];
    #pragma unroll
    for (int fm = 0; fm < 2; ++fm) {
      int ar = wm * 32 + fm * 16 + frow;
      ah[fm] = *reinterpret_cast<const bf16x8*>(&lds[0][ar * 40 + fkg * 8]);
      al[fm] = *reinterpret_cast<const bf16x8*>(&lds[1][ar * 40 + fkg * 8]);
    }
    #pragma unroll
    for (int fn = 0; fn < 2; ++fn) {
      int br = wn * 32 + fn * 16 + frow;
      bh[fn] = *reinterpret_cast<const bf16x8*>(&lds[2][br * 40 + fkg * 8]);
      bl[fn] = *reinterpret_cast<const bf16x8*>(&lds[3][br * 40 + fkg * 8]);
    }
    #pragma unroll
    for (int fn = 0; fn < 2; ++fn)
      #pragma unroll
      for (int fm = 0; fm < 2; ++fm) {
        acc[fm][fn] = MFMA(ah[fm], bh[fn], acc[fm][fn], 0, 0, 0);
        acc[fm][fn] = MFMA(ah[fm], bl[fn], acc[fm][fn], 0, 0, 0);
        acc[fm][fn] = MFMA(al[fm], bh[fn], acc[fm][fn], 0, 0, 0);
      }
  }
  #pragma unroll
  for (int fm = 0; fm < 2; ++fm)
    #pragma unroll
    for (int fn = 0; fn < 2; ++fn) {
      int l = l0 + wm * 32 + fm * 16 + fkg * 4;
      int rp = rp0 + wn * 32 + fn * 16 + frow;
      u16 h[4], lo[4];
      #pragma unroll
      for (int r = 0; r < 4; ++r) splitf(acc[fm][fn][r], h[r], lo[r]);
      size_t o = ((size_t)(j * 2 + kind) * 192 + rp) * 128 + l;
      *reinterpret_cast<ushort4*>(&XLh[o]) = make_ushort4(h[0], h[1], h[2], h[3]);
      *reinterpret_cast<ushort4*>(&XLl[o]) = make_ushort4(lo[0], lo[1], lo[2], lo[3]);
    }
}

// ============ S3: harmonic product (VALU): OL[j][kind][bo][l] ============
__global__ __launch_bounds__(256) void k_s3(
    const u16* __restrict__ XLh, const u16* __restrict__ XLl,
    u16* __restrict__ OLh, u16* __restrict__ OLl) {
  const int j = blockIdx.x;
  const int l0 = blockIdx.y * 16;
  const int tid = threadIdx.x;
  __shared__ float Xs[2][128][17];
  __shared__ float Ws[2][64][17];
  for (int idx = tid; idx < 2 * 192 * 16; idx += 256) {
    int kind = idx / (192 * 16);
    int rem = idx - kind * (192 * 16);
    int rp = rem >> 4, lc = rem & 15;
    size_t src = ((size_t)(j * 2 + kind) * 192 + rp) * 128 + l0 + lc;
    float v = bf2f(XLh[src]) + bf2f(XLl[src]);
    if (rp < 128) Xs[kind][rp][lc] = v; else Ws[kind][rp - 128][lc] = v;
  }
  __syncthreads();
  const int bo = tid & 127, lg = tid >> 7;
  const int b = bo >> 3, o = bo & 7;
  u16 hr[8], lr[8], hi[8], li[8];
  #pragma unroll
  for (int i2 = 0; i2 < 8; ++i2) {
    int lc = lg * 8 + i2;
    float ar = 0.f, ai = 0.f;
    #pragma unroll
    for (int i = 0; i < 8; ++i) {
      float xr = Xs[0][b * 8 + i][lc], xi = Xs[1][b * 8 + i][lc];
      float wr = Ws[0][o * 8 + i][lc], wi = Ws[1][o * 8 + i][lc];
      ar += xr * wr - xi * wi;
      ai += xr * wi + xi * wr;
    }
    splitf(ar, hr[i2], lr[i2]);
    splitf(ai, hi[i2], li[i2]);
  }
  size_t o0 = ((size_t)(j * 2 + 0) * 128 + bo) * 128 + l0 + lg * 8;
  size_t o1 = ((size_t)(j * 2 + 1) * 128 + bo) * 128 + l0 + lg * 8;
  u16x8 v;
  #pragma unroll
  for (int i = 0; i < 8; ++i) v[i] = hr[i];
  *reinterpret_cast<u16x8*>(&OLh[o0]) = v;
  #pragma unroll
  for (int i = 0; i < 8; ++i) v[i] = lr[i];
  *reinterpret_cast<u16x8*>(&OLl[o0]) = v;
  #pragma unroll
  for (int i = 0; i < 8; ++i) v[i] = hi[i];
  *reinterpret_cast<u16x8*>(&OLh[o1]) = v;
  #pragma unroll
  for (int i = 0; i < 8; ++i) v[i] = li[i];
  *reinterpret_cast<u16x8*>(&OLl[o1]) = v;
}

// ============ S4: Legendre synthesis per j: C[t][n4] = sum_l Psyn[m][t][l] * OL[j][n4][l]
// n4 = kind*128 + bo. Out: G planes [j2=2j+kind][bo][t]  (coalesced ushort4)
__global__ __launch_bounds__(256) void k_s4(
    const u16* __restrict__ OLh, const u16* __restrict__ OLl,
    const float* __restrict__ Psyn,
    u16* __restrict__ Gh, u16* __restrict__ Gl) {
  const int j = blockIdx.x;
  const int t0 = (blockIdx.y & 1) * 64;
  const int nt = blockIdx.y >> 1;           // 0..3
  const int kind = nt >> 1;
  const int bo0 = (nt & 1) * 64;
  const int tid = threadIdx.x;
  const int sr = tid >> 2, sc = tid & 3;
  const int lane = tid & 63, wid = tid >> 6;
  const int wm = wid & 1, wn = wid >> 1;
  const int frow = lane & 15, fkg = lane >> 4;
  __shared__ u16 lds[4][2560];
  f32x4 acc[2][2] = {};
  const int m = 127 + 2 * j;
  const float* asrc = Psyn + ((size_t)m * 128 + t0 + sr) * 128;
  const u16* bbase_h = OLh + ((size_t)(j * 2 + kind) * 128 + bo0 + sr) * 128;
  const u16* bbase_l = OLl + ((size_t)(j * 2 + kind) * 128 + bo0 + sr) * 128;
  for (int k0 = 0; k0 < 128; k0 += 32) {
    __syncthreads();
    {
      const float4* ap = reinterpret_cast<const float4*>(asrc + k0 + sc * 8);
      float4 v0 = ap[0], v1 = ap[1];
      float vv[8] = {v0.x, v0.y, v0.z, v0.w, v1.x, v1.y, v1.z, v1.w};
      bf16x8 hv, lv;
      #pragma unroll
      for (int i = 0; i < 8; ++i) { u16 h, l; splitf(vv[i], h, l); hv[i] = (short)h; lv[i] = (short)l; }
      *reinterpret_cast<bf16x8*>(&lds[0][sr * 40 + sc * 8]) = hv;
      *reinterpret_cast<bf16x8*>(&lds[1][sr * 40 + sc * 8]) = lv;
    }
    {
      *reinterpret_cast<bf16x8*>(&lds[2][sr * 40 + sc * 8]) =
          *reinterpret_cast<const bf16x8*>(&bbase_h[k0 + sc * 8]);
      *reinterpret_cast<bf16x8*>(&lds[3][sr * 40 + sc * 8]) =
          *reinterpret_cast<const bf16x8*>(&bbase_l[k0 + sc * 8]);
    }
    __syncthreads();
    bf16x8 ah[2], al[2], bh[2], bl[2];
    #pragma unroll
    for (int fm = 0; fm < 2; ++fm) {
      int ar = wm * 32 + fm * 16 + frow;
      ah[fm] = *reinterpret_cast<const bf16x8*>(&lds[0][ar * 40 + fkg * 8]);
      al[fm] = *reinterpret_cast<const bf16x8*>(&lds[1][ar * 40 + fkg * 8]);
    }
    #pragma unroll
    for (int fn = 0; fn < 2; ++fn) {
      int br = wn * 32 + fn * 16 + frow;
      bh[fn] = *reinterpret_cast<const bf16x8*>(&lds[2][br * 40 + fkg * 8]);
      bl[fn] = *reinterpret_cast<const bf16x8*>(&lds[3][br * 40 + fkg * 8]);
    }
    #pragma unroll
    for (int fn = 0; fn < 2; ++fn)
      #pragma unroll
      for (int fm = 0; fm < 2; ++fm) {
        acc[fm][fn] = MFMA(ah[fm], bh[fn], acc[fm][fn], 0, 0, 0);
        acc[fm][fn] = MFMA(ah[fm], bl[fn], acc[fm][fn], 0, 0, 0);
        acc[fm][fn] = MFMA(al[fm], bh[fn], acc[fm][fn], 0, 0, 0);
      }
  }
  // store G[j2][bo][t]: rows t consecutive per reg -> ushort4, L2 write-combined
  #pragma unroll
  for (int fm = 0; fm < 2; ++fm)
    #pragma unroll
    for (int fn = 0; fn < 2; ++fn) {
      int tt = t0 + wm * 32 + fm * 16 + fkg * 4;
      int bo = bo0 + wn * 32 + fn * 16 + frow;
      u16 h[4], l[4];
      #pragma unroll
      for (int r = 0; r < 4; ++r) splitf(acc[fm][fn][r], h[r], l[r]);
      size_t o = ((size_t)(2 * j + kind) * 128 + bo) * 128 + tt;
      *reinterpret_cast<ushort4*>(&Gh[o]) = make_ushort4(h[0], h[1], h[2], h[3]);
      *reinterpret_cast<ushort4*>(&Gl[o]) = make_ushort4(l[0], l[1], l[2], l[3]);
    }
}

// ============ S5: inverse DFT: out[u5][p] = sum_k5 G-frag[u5][k5] * B5[k5][p] + bias
// G stored [j2][bo][t]; transpose-stage the A-tile in LDS.
__global__ __launch_bounds__(256) void k_s5(
    const u16* __restrict__ Gh, const u16* __restrict__ Gl,
    const u16* __restrict__ B5h, const u16* __restrict__ B5l,
    const float* __restrict__ bias, float* __restrict__ out) {
  const int u0 = blockIdx.x * 64;
  const int p0 = blockIdx.y * 64;
  const int bo = u0 >> 7;            // one bo per block (64-row tile within 128-t bo)
  const int t0 = u0 & 127;           // 0 or 64
  const int tid = threadIdx.x;
  const int sr = tid >> 2, sc = tid & 3;
  const int kk = tid >> 3;           // 0..31 (k index for A-transpose stage)
  const int tb8 = (tid & 7) * 8;     // 0..56 (t-offset, 8 at a time)
  const int lane = tid & 63, wid = tid >> 6;
  const int wm = wid & 1, wn = wid >> 1;
  const int frow = lane & 15, fkg = lane >> 4;
  __shared__ u16 lds[4][2560];
  f32x4 acc[2][2] = {};
  const u16* bbase_h = B5h + (size_t)(p0 + sr) * 128;
  const u16* bbase_l = B5l + (size_t)(p0 + sr) * 128;
  for (int k0 = 0; k0 < 128; k0 += 32) {
    __syncthreads();
    { // stage A: G[j2=k0+kk][bo][t0+tb8..+8] -> LDS [t-row][k] (transpose scatter)
      size_t src = ((size_t)(k0 + kk) * 128 + bo) * 128 + t0 + tb8;
      bf16x8 hv = *reinterpret_cast<const bf16x8*>(&Gh[src]);
      bf16x8 lv = *reinterpret_cast<const bf16x8*>(&Gl[src]);
      #pragma unroll
      for (int i = 0; i < 8; ++i) {
        lds[0][(tb8 + i) * 40 + kk] = (u16)(unsigned short)hv[i];
        lds[1][(tb8 + i) * 40 + kk] = (u16)(unsigned short)lv[i];
      }
    }
    { // stage B: B5 table [p][k]
      *reinterpret_cast<bf16x8*>(&lds[2][sr * 40 + sc * 8]) =
          *reinterpret_cast<const bf16x8*>(&bbase_h[k0 + sc * 8]);
      *reinterpret_cast<bf16x8*>(&lds[3][sr * 40 + sc * 8]) =
          *reinterpret_cast<const bf16x8*>(&bbase_l[k0 + sc * 8]);
    }
    __syncthreads();
    bf16x8 ah[2], al[2], bh[2], bl[2];
    #pragma unroll
    for (int fm = 0; fm < 2; ++fm) {
      int ar = wm * 32 + fm * 16 + frow;
      ah[fm] = *reinterpret_cast<const bf16x8*>(&lds[0][ar * 40 + fkg * 8]);
      al[fm] = *reinterpret_cast<const bf16x8*>(&lds[1][ar * 40 + fkg * 8]);
    }
    #pragma unroll
    for (int fn = 0; fn < 2; ++fn) {
      int br = wn * 32 + fn * 16 + frow;
      bh[fn] = *reinterpret_cast<const bf16x8*>(&lds[2][br * 40 + fkg * 8]);
      bl[fn] = *reinterpret_cast<const bf16x8*>(&lds[3][br * 40 + fkg * 8]);
    }
    #pragma unroll
    for (int fn = 0; fn < 2; ++fn)
      #pragma unroll
      for (int fm = 0; fm < 2; ++fm) {
        acc[fm][fn] = MFMA(ah[fm], bh[fn], acc[fm][fn], 0, 0, 0);
        acc[fm][fn] = MFMA(ah[fm], bl[fn], acc[fm][fn], 0, 0, 0);
        acc[fm][fn] = MFMA(al[fm], bh[fn], acc[fm][fn], 0, 0, 0);
      }
  }
  const float bv = bias[bo & 7];
  #pragma unroll
  for (int fm = 0; fm < 2; ++fm)
    #pragma unroll
    for (int fn = 0; fn < 2; ++fn) {
      int u5 = u0 + wm * 32 + fm * 16 + fkg * 4;
      int p = p0 + wn * 32 + fn * 16 + frow;
      int t = u5 & 127;
      if (p < 255) {
        #pragma unroll
        for (int r = 0; r < 4; ++r)
          out[((size_t)bo * 128 + t + r) * 255 + p] = acc[fm][fn][r] + bv;
      }
    }
}

extern "C" void kernel_launch(void* const* d_in, const int* in_sizes, int n_in,
                              void* d_out, int out_size, void* d_ws, size_t ws_size,
                              hipStream_t stream) {
  const float* x    = (const float*)d_in[0];
  const float* w    = (const float*)d_in[1];
  const float* bias = (const float*)d_in[2];
  const float* Psyn = (const float*)d_in[3];
  const float* Pinv = (const float*)d_in[4];
  float* out = (float*)d_out;

  u16* ws = (u16*)d_ws;
  // Dedicated table region (never aliased): 4 * 32768 u16 = 256 KiB
  u16* B1h = ws;
  u16* B1l = ws + 32768;
  u16* B5h = ws + 2 * 32768;
  u16* B5l = ws + 3 * 32768;
  u16* base = ws + 4 * 32768;
  const size_t PLX = 3145728;   // 64*2*192*128
  u16* Xh  = base;
  u16* Xl  = base + PLX;
  u16* XLh = base + 2 * PLX;
  u16* XLl = base + 3 * PLX;
  // OL reuses X region head (X dead after S2): 64*2*128*128 = 2097152 u16 < PLX. OK.
  u16* OLh = Xh;
  u16* OLl = Xl;
  // G reuses XL region head (XL dead after S3): 128*128*128 = 2097152 u16 < PLX. OK.
  u16* Gh = XLh;
  u16* Gl = XLl;

  k_tab<<<256, 256, 0, stream>>>(B1h, B1l, B5h, B5l);
  k_s1<<<dim3(384, 2), 256, 0, stream>>>(x, w, B1h, B1l, Xh, Xl);
  k_s2<<<dim3(64, 12), 256, 0, stream>>>(Xh, Xl, Pinv, XLh, XLl);
  k_s3<<<dim3(64, 8), 256, 0, stream>>>(XLh, XLl, OLh, OLl);
  k_s4<<<dim3(64, 8), 256, 0, stream>>>(OLh, OLl, Psyn, Gh, Gl);
  k_s5<<<dim3(256, 4), 256, 0, stream>>>(Gh, Gl, B5h, B5l, bias, out);
}

// Round 11
// 156.311 us; speedup vs baseline: 2.0545x; 1.0118x over previous
//
#include <hip/hip_runtime.h>

#define PI_ 3.14159265358979323846

typedef __attribute__((ext_vector_type(8))) short bf16x8;
typedef __attribute__((ext_vector_type(4))) float f32x4;
typedef __attribute__((ext_vector_type(8))) unsigned short u16x8;
typedef unsigned short u16;

__device__ inline u16 f2bf(float f) {
  unsigned u = __float_as_uint(f);
  unsigned r = (u + 0x7FFFu + ((u >> 16) & 1u)) >> 16;
  return (u16)r;
}
__device__ inline float bf2f(u16 h) { return __uint_as_float(((unsigned)h) << 16); }
__device__ inline void splitf(float v, u16& h, u16& l) {
  h = f2bf(v);
  l = f2bf(v - bf2f(h));
}

// ============ tables (dedicated ws region, no aliasing) ============
__global__ void k_tab(u16* __restrict__ B1h, u16* __restrict__ B1l,
                      u16* __restrict__ B5h, u16* __restrict__ B5l) {
  int idx = blockIdx.x * 256 + threadIdx.x;
  if (idx < 128 * 256) {
    int n = idx >> 8, p = idx & 255;
    int j = n >> 1, kind = n & 1;
    double ang = (2.0 * PI_ / 255.0) * (double)(2 * j) * (double)p;
    double v = (p < 255) ? (kind ? -sin(ang) : cos(ang)) * (1.0 / 255.0) : 0.0;
    u16 h, l; splitf((float)v, h, l);
    B1h[idx] = h; B1l[idx] = l;
  } else {
    int i2 = idx - 128 * 256;
    if (i2 >= 256 * 128) return;
    int p = i2 >> 7, k = i2 & 127;
    int j = k >> 1, kind = k & 1;
    double ang = (2.0 * PI_ / 255.0) * (double)(2 * j) * (double)p;
    double sc = (j == 0) ? 1.0 : 2.0;
    double v = (p < 255) ? sc * (kind ? -sin(ang) : cos(ang)) : 0.0;
    u16 h, l; splitf((float)v, h, l);
    B5h[i2] = h; B5l[i2] = l;
  }
}

#define MFMA __builtin_amdgcn_mfma_f32_16x16x32_bf16

// All GEMM kernels: 32(M) x 128(N) tile, 256 threads = 4 waves (one 32-col
// N-quarter each), acc[2][2] fragments, K-chunk 32, LDS stride 40 u16.

// ============ S1: fwd DFT: C[u][n] = sum_p in[u][p] * B1[n][p] ============
__global__ __launch_bounds__(256) void k_s1(
    const float* __restrict__ x, const float* __restrict__ w,
    const u16* __restrict__ B1h, const u16* __restrict__ B1l,
    u16* __restrict__ Xh, u16* __restrict__ Xl) {
  const int u0 = blockIdx.x * 32;
  const int tid = threadIdx.x;
  const int lane = tid & 63, wid = tid >> 6;
  const int frow = lane & 15, fkg = lane >> 4;
  const int sc = tid & 3;
  __shared__ u16 Ah[32 * 40], Al[32 * 40], Bh[128 * 40], Bl[128 * 40];
  f32x4 acc[2][2] = {};
  const int ar = tid >> 2;               // A row (tid<128), B row base
  const int u = u0 + ar;
  const float* src = (tid < 128)
      ? ((u < 16384) ? (x + (size_t)u * 255) : (w + (size_t)(u - 16384) * 255))
      : x;
  for (int k0 = 0; k0 < 256; k0 += 32) {
    __syncthreads();
    if (tid < 128) {                     // A: f32 rows, split once per k-pass
      int kb = k0 + sc * 8;
      bf16x8 hv, lv;
      #pragma unroll
      for (int i = 0; i < 8; ++i) {
        int k = kb + i;
        float v = (k < 255) ? src[k] : 0.f;
        u16 h, l; splitf(v, h, l);
        hv[i] = (short)h; lv[i] = (short)l;
      }
      *reinterpret_cast<bf16x8*>(&Ah[ar * 40 + sc * 8]) = hv;
      *reinterpret_cast<bf16x8*>(&Al[ar * 40 + sc * 8]) = lv;
    }
    #pragma unroll
    for (int it = 0; it < 2; ++it) {     // B: pre-split table [n][256]
      int row = ar + it * 64;
      size_t o = (size_t)row * 256 + k0 + sc * 8;
      *reinterpret_cast<bf16x8*>(&Bh[row * 40 + sc * 8]) =
          *reinterpret_cast<const bf16x8*>(&B1h[o]);
      *reinterpret_cast<bf16x8*>(&Bl[row * 40 + sc * 8]) =
          *reinterpret_cast<const bf16x8*>(&B1l[o]);
    }
    __syncthreads();
    bf16x8 ah[2], al[2], bh[2], bl[2];
    #pragma unroll
    for (int fm = 0; fm < 2; ++fm) {
      int r = fm * 16 + frow;
      ah[fm] = *reinterpret_cast<const bf16x8*>(&Ah[r * 40 + fkg * 8]);
      al[fm] = *reinterpret_cast<const bf16x8*>(&Al[r * 40 + fkg * 8]);
    }
    #pragma unroll
    for (int fn = 0; fn < 2; ++fn) {
      int r = wid * 32 + fn * 16 + frow;
      bh[fn] = *reinterpret_cast<const bf16x8*>(&Bh[r * 40 + fkg * 8]);
      bl[fn] = *reinterpret_cast<const bf16x8*>(&Bl[r * 40 + fkg * 8]);
    }
    #pragma unroll
    for (int fn = 0; fn < 2; ++fn)
      #pragma unroll
      for (int fm = 0; fm < 2; ++fm) {
        acc[fm][fn] = MFMA(ah[fm], bh[fn], acc[fm][fn], 0, 0, 0);
        acc[fm][fn] = MFMA(ah[fm], bl[fn], acc[fm][fn], 0, 0, 0);
        acc[fm][fn] = MFMA(al[fm], bh[fn], acc[fm][fn], 0, 0, 0);
      }
  }
  #pragma unroll
  for (int fm = 0; fm < 2; ++fm)
    #pragma unroll
    for (int fn = 0; fn < 2; ++fn) {
      int gm = u0 + fm * 16 + fkg * 4;
      int gn = wid * 32 + fn * 16 + frow;
      int j = gn >> 1, kind = gn & 1;
      int rp = (gm < 16384) ? (gm >> 7) : (128 + ((gm - 16384) >> 7));
      int tb = gm & 127;
      u16 h[4], l[4];
      #pragma unroll
      for (int r = 0; r < 4; ++r) splitf(acc[fm][fn][r], h[r], l[r]);
      size_t o = ((size_t)(j * 2 + kind) * 192 + rp) * 128 + tb;
      *reinterpret_cast<ushort4*>(&Xh[o]) = make_ushort4(h[0], h[1], h[2], h[3]);
      *reinterpret_cast<ushort4*>(&Xl[o]) = make_ushort4(l[0], l[1], l[2], l[3]);
    }
}

// ============ S2: Legendre analysis: C[l][n2] = sum_t Pinv[m][l][t] X[j][n2][t]
__global__ __launch_bounds__(256) void k_s2(
    const u16* __restrict__ Xh, const u16* __restrict__ Xl,
    const float* __restrict__ Pinv,
    u16* __restrict__ XLh, u16* __restrict__ XLl) {
  const int j = blockIdx.x;
  const int lt = blockIdx.y & 3;         // 4 l-tiles of 32
  const int nt = blockIdx.y >> 2;        // 3 n2-tiles of 128
  const int l0 = lt * 32;
  const int tid = threadIdx.x;
  const int lane = tid & 63, wid = tid >> 6;
  const int frow = lane & 15, fkg = lane >> 4;
  const int sc = tid & 3;
  const int ar = tid >> 2;
  __shared__ u16 Ah[32 * 40], Al[32 * 40], Bh[128 * 40], Bl[128 * 40];
  f32x4 acc[2][2] = {};
  const int m = 127 + 2 * j;
  const float* asrc = Pinv + ((size_t)m * 128 + l0 + ar) * 128;
  for (int k0 = 0; k0 < 128; k0 += 32) {
    __syncthreads();
    if (tid < 128) {
      const float4* ap = reinterpret_cast<const float4*>(asrc + k0 + sc * 8);
      float4 v0 = ap[0], v1 = ap[1];
      float vv[8] = {v0.x, v0.y, v0.z, v0.w, v1.x, v1.y, v1.z, v1.w};
      bf16x8 hv, lv;
      #pragma unroll
      for (int i = 0; i < 8; ++i) { u16 h, l; splitf(vv[i], h, l); hv[i] = (short)h; lv[i] = (short)l; }
      *reinterpret_cast<bf16x8*>(&Ah[ar * 40 + sc * 8]) = hv;
      *reinterpret_cast<bf16x8*>(&Al[ar * 40 + sc * 8]) = lv;
    }
    #pragma unroll
    for (int it = 0; it < 2; ++it) {
      int row = ar + it * 64;
      int n2 = nt * 128 + row;
      int kd = (n2 >= 192) ? 1 : 0;
      int rp = n2 - 192 * kd;
      size_t o = ((size_t)(j * 2 + kd) * 192 + rp) * 128 + k0 + sc * 8;
      *reinterpret_cast<bf16x8*>(&Bh[row * 40 + sc * 8]) =
          *reinterpret_cast<const bf16x8*>(&Xh[o]);
      *reinterpret_cast<bf16x8*>(&Bl[row * 40 + sc * 8]) =
          *reinterpret_cast<const bf16x8*>(&Xl[o]);
    }
    __syncthreads();
    bf16x8 ah[2], al[2], bh[2], bl[2];
    #pragma unroll
    for (int fm = 0; fm < 2; ++fm) {
      int r = fm * 16 + frow;
      ah[fm] = *reinterpret_cast<const bf16x8*>(&Ah[r * 40 + fkg * 8]);
      al[fm] = *reinterpret_cast<const bf16x8*>(&Al[r * 40 + fkg * 8]);
    }
    #pragma unroll
    for (int fn = 0; fn < 2; ++fn) {
      int r = wid * 32 + fn * 16 + frow;
      bh[fn] = *reinterpret_cast<const bf16x8*>(&Bh[r * 40 + fkg * 8]);
      bl[fn] = *reinterpret_cast<const bf16x8*>(&Bl[r * 40 + fkg * 8]);
    }
    #pragma unroll
    for (int fn = 0; fn < 2; ++fn)
      #pragma unroll
      for (int fm = 0; fm < 2; ++fm) {
        acc[fm][fn] = MFMA(ah[fm], bh[fn], acc[fm][fn], 0, 0, 0);
        acc[fm][fn] = MFMA(ah[fm], bl[fn], acc[fm][fn], 0, 0, 0);
        acc[fm][fn] = MFMA(al[fm], bh[fn], acc[fm][fn], 0, 0, 0);
      }
  }
  #pragma unroll
  for (int fm = 0; fm < 2; ++fm)
    #pragma unroll
    for (int fn = 0; fn < 2; ++fn) {
      int l = l0 + fm * 16 + fkg * 4;
      int n2 = nt * 128 + wid * 32 + fn * 16 + frow;
      int kd = (n2 >= 192) ? 1 : 0;
      int rp = n2 - 192 * kd;
      u16 h[4], lo[4];
      #pragma unroll
      for (int r = 0; r < 4; ++r) splitf(acc[fm][fn][r], h[r], lo[r]);
      size_t o = ((size_t)(j * 2 + kd) * 192 + rp) * 128 + l;
      *reinterpret_cast<ushort4*>(&XLh[o]) = make_ushort4(h[0], h[1], h[2], h[3]);
      *reinterpret_cast<ushort4*>(&XLl[o]) = make_ushort4(lo[0], lo[1], lo[2], lo[3]);
    }
}

// ============ S3: harmonic product (VALU): OL[j][kind][bo][l] ============
__global__ __launch_bounds__(256) void k_s3(
    const u16* __restrict__ XLh, const u16* __restrict__ XLl,
    u16* __restrict__ OLh, u16* __restrict__ OLl) {
  const int j = blockIdx.x;
  const int l0 = blockIdx.y * 16;
  const int tid = threadIdx.x;
  __shared__ float Xs[2][128][17];
  __shared__ float Ws[2][64][17];
  for (int idx = tid; idx < 2 * 192 * 16; idx += 256) {
    int kind = idx / (192 * 16);
    int rem = idx - kind * (192 * 16);
    int rp = rem >> 4, lc = rem & 15;
    size_t src = ((size_t)(j * 2 + kind) * 192 + rp) * 128 + l0 + lc;
    float v = bf2f(XLh[src]) + bf2f(XLl[src]);
    if (rp < 128) Xs[kind][rp][lc] = v; else Ws[kind][rp - 128][lc] = v;
  }
  __syncthreads();
  const int bo = tid & 127, lg = tid >> 7;
  const int b = bo >> 3, o = bo & 7;
  u16 hr[8], lr[8], hi[8], li[8];
  #pragma unroll
  for (int i2 = 0; i2 < 8; ++i2) {
    int lc = lg * 8 + i2;
    float ar = 0.f, ai = 0.f;
    #pragma unroll
    for (int i = 0; i < 8; ++i) {
      float xr = Xs[0][b * 8 + i][lc], xi = Xs[1][b * 8 + i][lc];
      float wr = Ws[0][o * 8 + i][lc], wi = Ws[1][o * 8 + i][lc];
      ar += xr * wr - xi * wi;
      ai += xr * wi + xi * wr;
    }
    splitf(ar, hr[i2], lr[i2]);
    splitf(ai, hi[i2], li[i2]);
  }
  size_t o0 = ((size_t)(j * 2 + 0) * 128 + bo) * 128 + l0 + lg * 8;
  size_t o1 = ((size_t)(j * 2 + 1) * 128 + bo) * 128 + l0 + lg * 8;
  u16x8 v;
  #pragma unroll
  for (int i = 0; i < 8; ++i) v[i] = hr[i];
  *reinterpret_cast<u16x8*>(&OLh[o0]) = v;
  #pragma unroll
  for (int i = 0; i < 8; ++i) v[i] = lr[i];
  *reinterpret_cast<u16x8*>(&OLl[o0]) = v;
  #pragma unroll
  for (int i = 0; i < 8; ++i) v[i] = hi[i];
  *reinterpret_cast<u16x8*>(&OLh[o1]) = v;
  #pragma unroll
  for (int i = 0; i < 8; ++i) v[i] = li[i];
  *reinterpret_cast<u16x8*>(&OLl[o1]) = v;
}

// ============ S4: Legendre synthesis: C[t][n4] = sum_l Psyn[m][t][l] OL[j][n4][l]
// Out G[j2][bo][t] coalesced.
__global__ __launch_bounds__(256) void k_s4(
    const u16* __restrict__ OLh, const u16* __restrict__ OLl,
    const float* __restrict__ Psyn,
    u16* __restrict__ Gh, u16* __restrict__ Gl) {
  const int j = blockIdx.x;
  const int tt = blockIdx.y & 3;         // 4 t-tiles of 32
  const int nt = blockIdx.y >> 2;        // 2 n4-tiles of 128 (= kind)
  const int t0 = tt * 32;
  const int tid = threadIdx.x;
  const int lane = tid & 63, wid = tid >> 6;
  const int frow = lane & 15, fkg = lane >> 4;
  const int sc = tid & 3;
  const int ar = tid >> 2;
  __shared__ u16 Ah[32 * 40], Al[32 * 40], Bh[128 * 40], Bl[128 * 40];
  f32x4 acc[2][2] = {};
  const int m = 127 + 2 * j;
  const float* asrc = Psyn + ((size_t)m * 128 + t0 + ar) * 128;
  for (int k0 = 0; k0 < 128; k0 += 32) {
    __syncthreads();
    if (tid < 128) {
      const float4* ap = reinterpret_cast<const float4*>(asrc + k0 + sc * 8);
      float4 v0 = ap[0], v1 = ap[1];
      float vv[8] = {v0.x, v0.y, v0.z, v0.w, v1.x, v1.y, v1.z, v1.w};
      bf16x8 hv, lv;
      #pragma unroll
      for (int i = 0; i < 8; ++i) { u16 h, l; splitf(vv[i], h, l); hv[i] = (short)h; lv[i] = (short)l; }
      *reinterpret_cast<bf16x8*>(&Ah[ar * 40 + sc * 8]) = hv;
      *reinterpret_cast<bf16x8*>(&Al[ar * 40 + sc * 8]) = lv;
    }
    #pragma unroll
    for (int it = 0; it < 2; ++it) {
      int row = ar + it * 64;
      size_t o = ((size_t)(j * 2 + nt) * 128 + row) * 128 + k0 + sc * 8;
      *reinterpret_cast<bf16x8*>(&Bh[row * 40 + sc * 8]) =
          *reinterpret_cast<const bf16x8*>(&OLh[o]);
      *reinterpret_cast<bf16x8*>(&Bl[row * 40 + sc * 8]) =
          *reinterpret_cast<const bf16x8*>(&OLl[o]);
    }
    __syncthreads();
    bf16x8 ah[2], al[2], bh[2], bl[2];
    #pragma unroll
    for (int fm = 0; fm < 2; ++fm) {
      int r = fm * 16 + frow;
      ah[fm] = *reinterpret_cast<const bf16x8*>(&Ah[r * 40 + fkg * 8]);
      al[fm] = *reinterpret_cast<const bf16x8*>(&Al[r * 40 + fkg * 8]);
    }
    #pragma unroll
    for (int fn = 0; fn < 2; ++fn) {
      int r = wid * 32 + fn * 16 + frow;
      bh[fn] = *reinterpret_cast<const bf16x8*>(&Bh[r * 40 + fkg * 8]);
      bl[fn] = *reinterpret_cast<const bf16x8*>(&Bl[r * 40 + fkg * 8]);
    }
    #pragma unroll
    for (int fn = 0; fn < 2; ++fn)
      #pragma unroll
      for (int fm = 0; fm < 2; ++fm) {
        acc[fm][fn] = MFMA(ah[fm], bh[fn], acc[fm][fn], 0, 0, 0);
        acc[fm][fn] = MFMA(ah[fm], bl[fn], acc[fm][fn], 0, 0, 0);
        acc[fm][fn] = MFMA(al[fm], bh[fn], acc[fm][fn], 0, 0, 0);
      }
  }
  #pragma unroll
  for (int fm = 0; fm < 2; ++fm)
    #pragma unroll
    for (int fn = 0; fn < 2; ++fn) {
      int t = t0 + fm * 16 + fkg * 4;
      int bo = wid * 32 + fn * 16 + frow;
      u16 h[4], l[4];
      #pragma unroll
      for (int r = 0; r < 4; ++r) splitf(acc[fm][fn][r], h[r], l[r]);
      size_t o = ((size_t)(2 * j + nt) * 128 + bo) * 128 + t;
      *reinterpret_cast<ushort4*>(&Gh[o]) = make_ushort4(h[0], h[1], h[2], h[3]);
      *reinterpret_cast<ushort4*>(&Gl[o]) = make_ushort4(l[0], l[1], l[2], l[3]);
    }
}

// ============ S5: inverse DFT: out[u5][p] = sum_k5 G[k5][bo][t] B5[p][k5] + bias
__global__ __launch_bounds__(256) void k_s5(
    const u16* __restrict__ Gh, const u16* __restrict__ Gl,
    const u16* __restrict__ B5h, const u16* __restrict__ B5l,
    const float* __restrict__ bias, float* __restrict__ out) {
  const int u0 = blockIdx.x * 32;
  const int p0 = blockIdx.y * 128;
  const int bo = u0 >> 7;
  const int t0 = u0 & 127;
  const int tid = threadIdx.x;
  const int lane = tid & 63, wid = tid >> 6;
  const int frow = lane & 15, fkg = lane >> 4;
  const int sc = tid & 3;
  const int ar = tid >> 2;
  const int kk = tid >> 3;              // 0..31 (k for A transpose)
  const int t4 = (tid & 7) * 4;         // 4 t's per thread
  __shared__ u16 Ah[32 * 40], Al[32 * 40], Bh[128 * 40], Bl[128 * 40];
  f32x4 acc[2][2] = {};
  for (int k0 = 0; k0 < 128; k0 += 32) {
    __syncthreads();
    { // A: G[j2=k0+kk][bo][t0+t4..+4] -> LDS [t][k] transpose scatter
      size_t src = ((size_t)(k0 + kk) * 128 + bo) * 128 + t0 + t4;
      ushort4 hv = *reinterpret_cast<const ushort4*>(&Gh[src]);
      ushort4 lv = *reinterpret_cast<const ushort4*>(&Gl[src]);
      Ah[(t4 + 0) * 40 + kk] = hv.x; Al[(t4 + 0) * 40 + kk] = lv.x;
      Ah[(t4 + 1) * 40 + kk] = hv.y; Al[(t4 + 1) * 40 + kk] = lv.y;
      Ah[(t4 + 2) * 40 + kk] = hv.z; Al[(t4 + 2) * 40 + kk] = lv.z;
      Ah[(t4 + 3) * 40 + kk] = hv.w; Al[(t4 + 3) * 40 + kk] = lv.w;
    }
    #pragma unroll
    for (int it = 0; it < 2; ++it) {     // B: B5 [p=256][k=128]
      int row = ar + it * 64;
      size_t o = (size_t)(p0 + row) * 128 + k0 + sc * 8;
      *reinterpret_cast<bf16x8*>(&Bh[row * 40 + sc * 8]) =
          *reinterpret_cast<const bf16x8*>(&B5h[o]);
      *reinterpret_cast<bf16x8*>(&Bl[row * 40 + sc * 8]) =
          *reinterpret_cast<const bf16x8*>(&B5l[o]);
    }
    __syncthreads();
    bf16x8 ah[2], al[2], bh[2], bl[2];
    #pragma unroll
    for (int fm = 0; fm < 2; ++fm) {
      int r = fm * 16 + frow;
      ah[fm] = *reinterpret_cast<const bf16x8*>(&Ah[r * 40 + fkg * 8]);
      al[fm] = *reinterpret_cast<const bf16x8*>(&Al[r * 40 + fkg * 8]);
    }
    #pragma unroll
    for (int fn = 0; fn < 2; ++fn) {
      int r = wid * 32 + fn * 16 + frow;
      bh[fn] = *reinterpret_cast<const bf16x8*>(&Bh[r * 40 + fkg * 8]);
      bl[fn] = *reinterpret_cast<const bf16x8*>(&Bl[r * 40 + fkg * 8]);
    }
    #pragma unroll
    for (int fn = 0; fn < 2; ++fn)
      #pragma unroll
      for (int fm = 0; fm < 2; ++fm) {
        acc[fm][fn] = MFMA(ah[fm], bh[fn], acc[fm][fn], 0, 0, 0);
        acc[fm][fn] = MFMA(ah[fm], bl[fn], acc[fm][fn], 0, 0, 0);
        acc[fm][fn] = MFMA(al[fm], bh[fn], acc[fm][fn], 0, 0, 0);
      }
  }
  const float bv = bias[bo & 7];
  #pragma unroll
  for (int fm = 0; fm < 2; ++fm)
    #pragma unroll
    for (int fn = 0; fn < 2; ++fn) {
      int u5 = u0 + fm * 16 + fkg * 4;
      int p = p0 + wid * 32 + fn * 16 + frow;
      int t = u5 & 127;
      if (p < 255) {
        #pragma unroll
        for (int r = 0; r < 4; ++r)
          out[((size_t)bo * 128 + t + r) * 255 + p] = acc[fm][fn][r] + bv;
      }
    }
}

extern "C" void kernel_launch(void* const* d_in, const int* in_sizes, int n_in,
                              void* d_out, int out_size, void* d_ws, size_t ws_size,
                              hipStream_t stream) {
  const float* x    = (const float*)d_in[0];
  const float* w    = (const float*)d_in[1];
  const float* bias = (const float*)d_in[2];
  const float* Psyn = (const float*)d_in[3];
  const float* Pinv = (const float*)d_in[4];
  float* out = (float*)d_out;

  u16* ws = (u16*)d_ws;
  // Dedicated table region (never aliased): 4 * 32768 u16 = 256 KiB
  u16* B1h = ws;
  u16* B1l = ws + 32768;
  u16* B5h = ws + 2 * 32768;
  u16* B5l = ws + 3 * 32768;
  u16* base = ws + 4 * 32768;
  const size_t PLX = 3145728;   // 64*2*192*128
  u16* Xh  = base;
  u16* Xl  = base + PLX;
  u16* XLh = base + 2 * PLX;
  u16* XLl = base + 3 * PLX;
  u16* OLh = Xh;                // X dead after S2; OL = 2.097M u16 < PLX
  u16* OLl = Xl;
  u16* Gh = XLh;                // XL dead after S3; G = 2.097M u16 < PLX
  u16* Gl = XLl;

  k_tab<<<256, 256, 0, stream>>>(B1h, B1l, B5h, B5l);
  k_s1<<<768, 256, 0, stream>>>(x, w, B1h, B1l, Xh, Xl);
  k_s2<<<dim3(64, 12), 256, 0, stream>>>(Xh, Xl, Pinv, XLh, XLl);
  k_s3<<<dim3(64, 8), 256, 0, stream>>>(XLh, XLl, OLh, OLl);
  k_s4<<<dim3(64, 8), 256, 0, stream>>>(OLh, OLl, Psyn, Gh, Gl);
  k_s5<<<dim3(512, 2), 256, 0, stream>>>(Gh, Gl, B5h, B5l, bias, out);
}

// Round 14
// 151.443 us; speedup vs baseline: 2.1206x; 1.0321x over previous
//
#include <hip/hip_runtime.h>

#define PI_ 3.14159265358979323846

typedef __attribute__((ext_vector_type(8))) short bf16x8;
typedef __attribute__((ext_vector_type(4))) float f32x4;
typedef __attribute__((ext_vector_type(8))) unsigned short u16x8;
typedef unsigned short u16;

__device__ inline u16 f2bf(float f) {
  unsigned u = __float_as_uint(f);
  unsigned r = (u + 0x7FFFu + ((u >> 16) & 1u)) >> 16;
  return (u16)r;
}
__device__ inline float bf2f(u16 h) { return __uint_as_float(((unsigned)h) << 16); }
__device__ inline void splitf(float v, u16& h, u16& l) {
  h = f2bf(v);
  l = f2bf(v - bf2f(h));
}

// ============ tables (dedicated ws region, no aliasing) ============
__global__ void k_tab(u16* __restrict__ B1h, u16* __restrict__ B1l,
                      u16* __restrict__ B5h, u16* __restrict__ B5l) {
  int idx = blockIdx.x * 256 + threadIdx.x;
  if (idx < 128 * 256) {
    int n = idx >> 8, p = idx & 255;
    int j = n >> 1, kind = n & 1;
    double ang = (2.0 * PI_ / 255.0) * (double)(2 * j) * (double)p;
    double v = (p < 255) ? (kind ? -sin(ang) : cos(ang)) * (1.0 / 255.0) : 0.0;
    u16 h, l; splitf((float)v, h, l);
    B1h[idx] = h; B1l[idx] = l;
  } else {
    int i2 = idx - 128 * 256;
    if (i2 >= 256 * 128) return;
    int p = i2 >> 7, k = i2 & 127;
    int j = k >> 1, kind = k & 1;
    double ang = (2.0 * PI_ / 255.0) * (double)(2 * j) * (double)p;
    double sc = (j == 0) ? 1.0 : 2.0;
    double v = (p < 255) ? sc * (kind ? -sin(ang) : cos(ang)) : 0.0;
    u16 h, l; splitf((float)v, h, l);
    B5h[i2] = h; B5l[i2] = l;
  }
}

#define MFMA __builtin_amdgcn_mfma_f32_16x16x32_bf16

// GEMM kernels: 32(M) x 128(N) tile, 4 waves, acc[2][2], K-chunk 32,
// LDS stride 40 u16.  Register-prefetch double-buffering — chunk c+1's
// global loads issue right after the LDS-ready barrier, hiding their latency
// under chunk c's ds_read+MFMA.

// ============ S1: fwd DFT: C[u][n] = sum_p in[u][p] * B1[n][p] ============
__global__ __launch_bounds__(256) void k_s1(
    const float* __restrict__ x, const float* __restrict__ w,
    const u16* __restrict__ B1h, const u16* __restrict__ B1l,
    u16* __restrict__ Xh, u16* __restrict__ Xl) {
  const int u0 = blockIdx.x * 32;
  const int tid = threadIdx.x;
  const int lane = tid & 63, wid = tid >> 6;
  const int frow = lane & 15, fkg = lane >> 4;
  const int sc = tid & 3;
  const int ar = tid >> 2;
  __shared__ u16 Ah[32 * 40], Al[32 * 40], Bh[128 * 40], Bl[128 * 40];
  f32x4 acc[2][2] = {};
  const int u = u0 + ar;
  const float* src = (tid < 128)
      ? ((u < 16384) ? (x + (size_t)u * 255) : (w + (size_t)(u - 16384) * 255))
      : x;
  float pa[8];
  bf16x8 pbh[2], pbl[2];
  auto load_chunk = [&](int k0) {
    if (tid < 128) {
      int kb = k0 + sc * 8;
      #pragma unroll
      for (int i = 0; i < 8; ++i) {
        int k = kb + i;
        pa[i] = (k < 255) ? src[k] : 0.f;
      }
    }
    #pragma unroll
    for (int it = 0; it < 2; ++it) {
      int row = ar + it * 64;
      size_t o = (size_t)row * 256 + k0 + sc * 8;
      pbh[it] = *reinterpret_cast<const bf16x8*>(&B1h[o]);
      pbl[it] = *reinterpret_cast<const bf16x8*>(&B1l[o]);
    }
  };
  load_chunk(0);
  for (int c = 0; c < 8; ++c) {
    __syncthreads();
    if (tid < 128) {
      bf16x8 hv, lv;
      #pragma unroll
      for (int i = 0; i < 8; ++i) { u16 h, l; splitf(pa[i], h, l); hv[i] = (short)h; lv[i] = (short)l; }
      *reinterpret_cast<bf16x8*>(&Ah[ar * 40 + sc * 8]) = hv;
      *reinterpret_cast<bf16x8*>(&Al[ar * 40 + sc * 8]) = lv;
    }
    #pragma unroll
    for (int it = 0; it < 2; ++it) {
      int row = ar + it * 64;
      *reinterpret_cast<bf16x8*>(&Bh[row * 40 + sc * 8]) = pbh[it];
      *reinterpret_cast<bf16x8*>(&Bl[row * 40 + sc * 8]) = pbl[it];
    }
    __syncthreads();
    if (c + 1 < 8) load_chunk((c + 1) * 32);
    bf16x8 ah[2], al[2], bh[2], bl[2];
    #pragma unroll
    for (int fm = 0; fm < 2; ++fm) {
      int r = fm * 16 + frow;
      ah[fm] = *reinterpret_cast<const bf16x8*>(&Ah[r * 40 + fkg * 8]);
      al[fm] = *reinterpret_cast<const bf16x8*>(&Al[r * 40 + fkg * 8]);
    }
    #pragma unroll
    for (int fn = 0; fn < 2; ++fn) {
      int r = wid * 32 + fn * 16 + frow;
      bh[fn] = *reinterpret_cast<const bf16x8*>(&Bh[r * 40 + fkg * 8]);
      bl[fn] = *reinterpret_cast<const bf16x8*>(&Bl[r * 40 + fkg * 8]);
    }
    #pragma unroll
    for (int fn = 0; fn < 2; ++fn)
      #pragma unroll
      for (int fm = 0; fm < 2; ++fm) {
        acc[fm][fn] = MFMA(ah[fm], bh[fn], acc[fm][fn], 0, 0, 0);
        acc[fm][fn] = MFMA(ah[fm], bl[fn], acc[fm][fn], 0, 0, 0);
        acc[fm][fn] = MFMA(al[fm], bh[fn], acc[fm][fn], 0, 0, 0);
      }
  }
  #pragma unroll
  for (int fm = 0; fm < 2; ++fm)
    #pragma unroll
    for (int fn = 0; fn < 2; ++fn) {
      int gm = u0 + fm * 16 + fkg * 4;
      int gn = wid * 32 + fn * 16 + frow;
      int j = gn >> 1, kind = gn & 1;
      int rp = (gm < 16384) ? (gm >> 7) : (128 + ((gm - 16384) >> 7));
      int tb = gm & 127;
      u16 h[4], l[4];
      #pragma unroll
      for (int r = 0; r < 4; ++r) splitf(acc[fm][fn][r], h[r], l[r]);
      size_t o = ((size_t)(j * 2 + kind) * 192 + rp) * 128 + tb;
      *reinterpret_cast<ushort4*>(&Xh[o]) = make_ushort4(h[0], h[1], h[2], h[3]);
      *reinterpret_cast<ushort4*>(&Xl[o]) = make_ushort4(l[0], l[1], l[2], l[3]);
    }
}

// ============ S2: Legendre analysis: C[l][n2] = sum_t Pinv[m][l][t] X[j][n2][t]
__global__ __launch_bounds__(256) void k_s2(
    const u16* __restrict__ Xh, const u16* __restrict__ Xl,
    const float* __restrict__ Pinv,
    u16* __restrict__ XLh, u16* __restrict__ XLl) {
  const int j = blockIdx.x;
  const int lt = blockIdx.y & 3;
  const int nt = blockIdx.y >> 2;
  const int l0 = lt * 32;
  const int tid = threadIdx.x;
  const int lane = tid & 63, wid = tid >> 6;
  const int frow = lane & 15, fkg = lane >> 4;
  const int sc = tid & 3;
  const int ar = tid >> 2;
  __shared__ u16 Ah[32 * 40], Al[32 * 40], Bh[128 * 40], Bl[128 * 40];
  f32x4 acc[2][2] = {};
  const int m = 127 + 2 * j;
  const float* asrc = Pinv + ((size_t)m * 128 + l0 + ar) * 128;
  float4 pa0, pa1;
  bf16x8 pbh[2], pbl[2];
  auto load_chunk = [&](int k0) {
    if (tid < 128) {
      const float4* ap = reinterpret_cast<const float4*>(asrc + k0 + sc * 8);
      pa0 = ap[0]; pa1 = ap[1];
    }
    #pragma unroll
    for (int it = 0; it < 2; ++it) {
      int row = ar + it * 64;
      int n2 = nt * 128 + row;
      int kd = (n2 >= 192) ? 1 : 0;
      int rp = n2 - 192 * kd;
      size_t o = ((size_t)(j * 2 + kd) * 192 + rp) * 128 + k0 + sc * 8;
      pbh[it] = *reinterpret_cast<const bf16x8*>(&Xh[o]);
      pbl[it] = *reinterpret_cast<const bf16x8*>(&Xl[o]);
    }
  };
  load_chunk(0);
  for (int c = 0; c < 4; ++c) {
    __syncthreads();
    if (tid < 128) {
      float vv[8] = {pa0.x, pa0.y, pa0.z, pa0.w, pa1.x, pa1.y, pa1.z, pa1.w};
      bf16x8 hv, lv;
      #pragma unroll
      for (int i = 0; i < 8; ++i) { u16 h, l; splitf(vv[i], h, l); hv[i] = (short)h; lv[i] = (short)l; }
      *reinterpret_cast<bf16x8*>(&Ah[ar * 40 + sc * 8]) = hv;
      *reinterpret_cast<bf16x8*>(&Al[ar * 40 + sc * 8]) = lv;
    }
    #pragma unroll
    for (int it = 0; it < 2; ++it) {
      int row = ar + it * 64;
      *reinterpret_cast<bf16x8*>(&Bh[row * 40 + sc * 8]) = pbh[it];
      *reinterpret_cast<bf16x8*>(&Bl[row * 40 + sc * 8]) = pbl[it];
    }
    __syncthreads();
    if (c + 1 < 4) load_chunk((c + 1) * 32);
    bf16x8 ah[2], al[2], bh[2], bl[2];
    #pragma unroll
    for (int fm = 0; fm < 2; ++fm) {
      int r = fm * 16 + frow;
      ah[fm] = *reinterpret_cast<const bf16x8*>(&Ah[r * 40 + fkg * 8]);
      al[fm] = *reinterpret_cast<const bf16x8*>(&Al[r * 40 + fkg * 8]);
    }
    #pragma unroll
    for (int fn = 0; fn < 2; ++fn) {
      int r = wid * 32 + fn * 16 + frow;
      bh[fn] = *reinterpret_cast<const bf16x8*>(&Bh[r * 40 + fkg * 8]);
      bl[fn] = *reinterpret_cast<const bf16x8*>(&Bl[r * 40 + fkg * 8]);
    }
    #pragma unroll
    for (int fn = 0; fn < 2; ++fn)
      #pragma unroll
      for (int fm = 0; fm < 2; ++fm) {
        acc[fm][fn] = MFMA(ah[fm], bh[fn], acc[fm][fn], 0, 0, 0);
        acc[fm][fn] = MFMA(ah[fm], bl[fn], acc[fm][fn], 0, 0, 0);
        acc[fm][fn] = MFMA(al[fm], bh[fn], acc[fm][fn], 0, 0, 0);
      }
  }
  #pragma unroll
  for (int fm = 0; fm < 2; ++fm)
    #pragma unroll
    for (int fn = 0; fn < 2; ++fn) {
      int l = l0 + fm * 16 + fkg * 4;
      int n2 = nt * 128 + wid * 32 + fn * 16 + frow;
      int kd = (n2 >= 192) ? 1 : 0;
      int rp = n2 - 192 * kd;
      u16 h[4], lo[4];
      #pragma unroll
      for (int r = 0; r < 4; ++r) splitf(acc[fm][fn][r], h[r], lo[r]);
      size_t o = ((size_t)(j * 2 + kd) * 192 + rp) * 128 + l;
      *reinterpret_cast<ushort4*>(&XLh[o]) = make_ushort4(h[0], h[1], h[2], h[3]);
      *reinterpret_cast<ushort4*>(&XLl[o]) = make_ushort4(lo[0], lo[1], lo[2], lo[3]);
    }
}

// ============ S3: harmonic product (VALU), vectorized staging ============
__global__ __launch_bounds__(256) void k_s3(
    const u16* __restrict__ XLh, const u16* __restrict__ XLl,
    u16* __restrict__ OLh, u16* __restrict__ OLl) {
  const int j = blockIdx.x;
  const int l0 = blockIdx.y * 16;
  const int tid = threadIdx.x;
  __shared__ float Xs[2][128][17];
  __shared__ float Ws[2][64][17];
  for (int idx = tid; idx < 2 * 192 * 2; idx += 256) {   // items of 8 u16
    int kind = (idx >= 384) ? 1 : 0;
    int rem = idx - kind * 384;
    int rp = rem >> 1, half = rem & 1;
    size_t src = ((size_t)(j * 2 + kind) * 192 + rp) * 128 + l0 + half * 8;
    u16x8 hv = *reinterpret_cast<const u16x8*>(&XLh[src]);
    u16x8 lv = *reinterpret_cast<const u16x8*>(&XLl[src]);
    #pragma unroll
    for (int i = 0; i < 8; ++i) {
      float v = bf2f(hv[i]) + bf2f(lv[i]);
      int lc = half * 8 + i;
      if (rp < 128) Xs[kind][rp][lc] = v; else Ws[kind][rp - 128][lc] = v;
    }
  }
  __syncthreads();
  const int bo = tid & 127, lg = tid >> 7;
  const int b = bo >> 3, o = bo & 7;
  u16 hr[8], lr[8], hi[8], li[8];
  #pragma unroll
  for (int i2 = 0; i2 < 8; ++i2) {
    int lc = lg * 8 + i2;
    float ar = 0.f, ai = 0.f;
    #pragma unroll
    for (int i = 0; i < 8; ++i) {
      float xr = Xs[0][b * 8 + i][lc], xi = Xs[1][b * 8 + i][lc];
      float wr = Ws[0][o * 8 + i][lc], wi = Ws[1][o * 8 + i][lc];
      ar += xr * wr - xi * wi;
      ai += xr * wi + xi * wr;
    }
    splitf(ar, hr[i2], lr[i2]);
    splitf(ai, hi[i2], li[i2]);
  }
  size_t o0 = ((size_t)(j * 2 + 0) * 128 + bo) * 128 + l0 + lg * 8;
  size_t o1 = ((size_t)(j * 2 + 1) * 128 + bo) * 128 + l0 + lg * 8;
  u16x8 v;
  #pragma unroll
  for (int i = 0; i < 8; ++i) v[i] = hr[i];
  *reinterpret_cast<u16x8*>(&OLh[o0]) = v;
  #pragma unroll
  for (int i = 0; i < 8; ++i) v[i] = lr[i];
  *reinterpret_cast<u16x8*>(&OLl[o0]) = v;
  #pragma unroll
  for (int i = 0; i < 8; ++i) v[i] = hi[i];
  *reinterpret_cast<u16x8*>(&OLh[o1]) = v;
  #pragma unroll
  for (int i = 0; i < 8; ++i) v[i] = li[i];
  *reinterpret_cast<u16x8*>(&OLl[o1]) = v;
}

// ============ S4: Legendre synthesis: out G[j2][bo][t] coalesced ============
__global__ __launch_bounds__(256) void k_s4(
    const u16* __restrict__ OLh, const u16* __restrict__ OLl,
    const float* __restrict__ Psyn,
    u16* __restrict__ Gh, u16* __restrict__ Gl) {
  const int j = blockIdx.x;
  const int tt = blockIdx.y & 3;
  const int nt = blockIdx.y >> 2;
  const int t0 = tt * 32;
  const int tid = threadIdx.x;
  const int lane = tid & 63, wid = tid >> 6;
  const int frow = lane & 15, fkg = lane >> 4;
  const int sc = tid & 3;
  const int ar = tid >> 2;
  __shared__ u16 Ah[32 * 40], Al[32 * 40], Bh[128 * 40], Bl[128 * 40];
  f32x4 acc[2][2] = {};
  const int m = 127 + 2 * j;
  const float* asrc = Psyn + ((size_t)m * 128 + t0 + ar) * 128;
  float4 pa0, pa1;
  bf16x8 pbh[2], pbl[2];
  auto load_chunk = [&](int k0) {
    if (tid < 128) {
      const float4* ap = reinterpret_cast<const float4*>(asrc + k0 + sc * 8);
      pa0 = ap[0]; pa1 = ap[1];
    }
    #pragma unroll
    for (int it = 0; it < 2; ++it) {
      int row = ar + it * 64;
      size_t o = ((size_t)(j * 2 + nt) * 128 + row) * 128 + k0 + sc * 8;
      pbh[it] = *reinterpret_cast<const bf16x8*>(&OLh[o]);
      pbl[it] = *reinterpret_cast<const bf16x8*>(&OLl[o]);
    }
  };
  load_chunk(0);
  for (int c = 0; c < 4; ++c) {
    __syncthreads();
    if (tid < 128) {
      float vv[8] = {pa0.x, pa0.y, pa0.z, pa0.w, pa1.x, pa1.y, pa1.z, pa1.w};
      bf16x8 hv, lv;
      #pragma unroll
      for (int i = 0; i < 8; ++i) { u16 h, l; splitf(vv[i], h, l); hv[i] = (short)h; lv[i] = (short)l; }
      *reinterpret_cast<bf16x8*>(&Ah[ar * 40 + sc * 8]) = hv;
      *reinterpret_cast<bf16x8*>(&Al[ar * 40 + sc * 8]) = lv;
    }
    #pragma unroll
    for (int it = 0; it < 2; ++it) {
      int row = ar + it * 64;
      *reinterpret_cast<bf16x8*>(&Bh[row * 40 + sc * 8]) = pbh[it];
      *reinterpret_cast<bf16x8*>(&Bl[row * 40 + sc * 8]) = pbl[it];
    }
    __syncthreads();
    if (c + 1 < 4) load_chunk((c + 1) * 32);
    bf16x8 ah[2], al[2], bh[2], bl[2];
    #pragma unroll
    for (int fm = 0; fm < 2; ++fm) {
      int r = fm * 16 + frow;
      ah[fm] = *reinterpret_cast<const bf16x8*>(&Ah[r * 40 + fkg * 8]);
      al[fm] = *reinterpret_cast<const bf16x8*>(&Al[r * 40 + fkg * 8]);
    }
    #pragma unroll
    for (int fn = 0; fn < 2; ++fn) {
      int r = wid * 32 + fn * 16 + frow;
      bh[fn] = *reinterpret_cast<const bf16x8*>(&Bh[r * 40 + fkg * 8]);
      bl[fn] = *reinterpret_cast<const bf16x8*>(&Bl[r * 40 + fkg * 8]);
    }
    #pragma unroll
    for (int fn = 0; fn < 2; ++fn)
      #pragma unroll
      for (int fm = 0; fm < 2; ++fm) {
        acc[fm][fn] = MFMA(ah[fm], bh[fn], acc[fm][fn], 0, 0, 0);
        acc[fm][fn] = MFMA(ah[fm], bl[fn], acc[fm][fn], 0, 0, 0);
        acc[fm][fn] = MFMA(al[fm], bh[fn], acc[fm][fn], 0, 0, 0);
      }
  }
  #pragma unroll
  for (int fm = 0; fm < 2; ++fm)
    #pragma unroll
    for (int fn = 0; fn < 2; ++fn) {
      int t = t0 + fm * 16 + fkg * 4;
      int bo = wid * 32 + fn * 16 + frow;
      u16 h[4], l[4];
      #pragma unroll
      for (int r = 0; r < 4; ++r) splitf(acc[fm][fn][r], h[r], l[r]);
      size_t o = ((size_t)(2 * j + nt) * 128 + bo) * 128 + t;
      *reinterpret_cast<ushort4*>(&Gh[o]) = make_ushort4(h[0], h[1], h[2], h[3]);
      *reinterpret_cast<ushort4*>(&Gl[o]) = make_ushort4(l[0], l[1], l[2], l[3]);
    }
}

// ============ S5: inverse DFT + bias ============
__global__ __launch_bounds__(256) void k_s5(
    const u16* __restrict__ Gh, const u16* __restrict__ Gl,
    const u16* __restrict__ B5h, const u16* __restrict__ B5l,
    const float* __restrict__ bias, float* __restrict__ out) {
  const int u0 = blockIdx.x * 32;
  const int p0 = blockIdx.y * 128;
  const int bo = u0 >> 7;
  const int t0 = u0 & 127;
  const int tid = threadIdx.x;
  const int lane = tid & 63, wid = tid >> 6;
  const int frow = lane & 15, fkg = lane >> 4;
  const int sc = tid & 3;
  const int ar = tid >> 2;
  const int kk = tid >> 3;
  const int t4 = (tid & 7) * 4;
  __shared__ u16 Ah[32 * 40], Al[32 * 40], Bh[128 * 40], Bl[128 * 40];
  f32x4 acc[2][2] = {};
  ushort4 pgh, pgl;
  bf16x8 pbh[2], pbl[2];
  auto load_chunk = [&](int k0) {
    size_t srcA = ((size_t)(k0 + kk) * 128 + bo) * 128 + t0 + t4;
    pgh = *reinterpret_cast<const ushort4*>(&Gh[srcA]);
    pgl = *reinterpret_cast<const ushort4*>(&Gl[srcA]);
    #pragma unroll
    for (int it = 0; it < 2; ++it) {
      int row = ar + it * 64;
      size_t o = (size_t)(p0 + row) * 128 + k0 + sc * 8;
      pbh[it] = *reinterpret_cast<const bf16x8*>(&B5h[o]);
      pbl[it] = *reinterpret_cast<const bf16x8*>(&B5l[o]);
    }
  };
  load_chunk(0);
  for (int c = 0; c < 4; ++c) {
    __syncthreads();
    Ah[(t4 + 0) * 40 + kk] = pgh.x; Al[(t4 + 0) * 40 + kk] = pgl.x;
    Ah[(t4 + 1) * 40 + kk] = pgh.y; Al[(t4 + 1) * 40 + kk] = pgl.y;
    Ah[(t4 + 2) * 40 + kk] = pgh.z; Al[(t4 + 2) * 40 + kk] = pgl.z;
    Ah[(t4 + 3) * 40 + kk] = pgh.w; Al[(t4 + 3) * 40 + kk] = pgl.w;
    #pragma unroll
    for (int it = 0; it < 2; ++it) {
      int row = ar + it * 64;
      *reinterpret_cast<bf16x8*>(&Bh[row * 40 + sc * 8]) = pbh[it];
      *reinterpret_cast<bf16x8*>(&Bl[row * 40 + sc * 8]) = pbl[it];
    }
    __syncthreads();
    if (c + 1 < 4) load_chunk((c + 1) * 32);
    bf16x8 ah[2], al[2], bh[2], bl[2];
    #pragma unroll
    for (int fm = 0; fm < 2; ++fm) {
      int r = fm * 16 + frow;
      ah[fm] = *reinterpret_cast<const bf16x8*>(&Ah[r * 40 + fkg * 8]);
      al[fm] = *reinterpret_cast<const bf16x8*>(&Al[r * 40 + fkg * 8]);
    }
    #pragma unroll
    for (int fn = 0; fn < 2; ++fn) {
      int r = wid * 32 + fn * 16 + frow;
      bh[fn] = *reinterpret_cast<const bf16x8*>(&Bh[r * 40 + fkg * 8]);
      bl[fn] = *reinterpret_cast<const bf16x8*>(&Bl[r * 40 + fkg * 8]);
    }
    #pragma unroll
    for (int fn = 0; fn < 2; ++fn)
      #pragma unroll
      for (int fm = 0; fm < 2; ++fm) {
        acc[fm][fn] = MFMA(ah[fm], bh[fn], acc[fm][fn], 0, 0, 0);
        acc[fm][fn] = MFMA(ah[fm], bl[fn], acc[fm][fn], 0, 0, 0);
        acc[fm][fn] = MFMA(al[fm], bh[fn], acc[fm][fn], 0, 0, 0);
      }
  }
  const float bv = bias[bo & 7];
  #pragma unroll
  for (int fm = 0; fm < 2; ++fm)
    #pragma unroll
    for (int fn = 0; fn < 2; ++fn) {
      int u5 = u0 + fm * 16 + fkg * 4;
      int p = p0 + wid * 32 + fn * 16 + frow;
      int t = u5 & 127;
      if (p < 255) {
        #pragma unroll
        for (int r = 0; r < 4; ++r)
          out[((size_t)bo * 128 + t + r) * 255 + p] = acc[fm][fn][r] + bv;
      }
    }
}

extern "C" void kernel_launch(void* const* d_in, const int* in_sizes, int n_in,
                              void* d_out, int out_size, void* d_ws, size_t ws_size,
                              hipStream_t stream) {
  const float* x    = (const float*)d_in[0];
  const float* w    = (const float*)d_in[1];
  const float* bias = (const float*)d_in[2];
  const float* Psyn = (const float*)d_in[3];
  const float* Pinv = (const float*)d_in[4];
  float* out = (float*)d_out;

  u16* ws = (u16*)d_ws;
  u16* B1h = ws;
  u16* B1l = ws + 32768;
  u16* B5h = ws + 2 * 32768;
  u16* B5l = ws + 3 * 32768;
  u16* base = ws + 4 * 32768;
  const size_t PLX = 3145728;   // 64*2*192*128
  u16* Xh  = base;
  u16* Xl  = base + PLX;
  u16* XLh = base + 2 * PLX;
  u16* XLl = base + 3 * PLX;
  u16* OLh = Xh;
  u16* OLl = Xl;
  u16* Gh = XLh;
  u16* Gl = XLl;

  k_tab<<<256, 256, 0, stream>>>(B1h, B1l, B5h, B5l);
  k_s1<<<768, 256, 0, stream>>>(x, w, B1h, B1l, Xh, Xl);
  k_s2<<<dim3(64, 12), 256, 0, stream>>>(Xh, Xl, Pinv, XLh, XLl);
  k_s3<<<dim3(64, 8), 256, 0, stream>>>(XLh, XLl, OLh, OLl);
  k_s4<<<dim3(64, 8), 256, 0, stream>>>(OLh, OLl, Psyn, Gh, Gl);
  k_s5<<<dim3(512, 2), 256, 0, stream>>>(Gh, Gl, B5h, B5l, bias, out);
}